// Round 1
// 395.977 us; speedup vs baseline: 1.0828x; 1.0828x over previous
//
#include <hip/hip_runtime.h>
#include <math.h>

#define NN 50000
#define NE 500000
#define NREL 4
#define D 128
#define RSZ 512                 // dst-range size (one bin)
#define NRANGE 98               // ceil(NN/512)
#define NBK (NREL * NRANGE)     // 392 sort blocks
#define BCAP 6144               // per-(range,rel) csr capacity (mean 5120, +14 sigma)
#define NCH 128                 // edge chunks per relation
#define CH 3907                 // edges per chunk (128*3907 >= 500000)
#define FCAP 96                 // frag capacity per (chunk,bin): mean 40, +9 sigma
#define CAST_BLKS 6250          // NN*D/4/256
static constexpr float BN_EPS = 1e-5f;

typedef __attribute__((ext_vector_type(8))) short short8;
typedef __attribute__((ext_vector_type(4))) float f32x4;

__device__ __forceinline__ float bf2f(unsigned short u) {
    return __uint_as_float(((unsigned)u) << 16);
}
__device__ __forceinline__ unsigned short f2bf(float f) {  // RTNE
    unsigned x = __float_as_uint(f);
    return (unsigned short)((x + 0x7FFFu + ((x >> 16) & 1u)) >> 16);
}

// ---------------- fused prologue: cast x->bf16, weight transpose+cast, bias sums, bnsum zero ----
__global__ __launch_bounds__(256) void k_pre(const float* __restrict__ x,
                                             const float* __restrict__ W1, const float* __restrict__ W2,
                                             const float* __restrict__ l1W, const float* __restrict__ b1,
                                             const float* __restrict__ b2,
                                             unsigned short* __restrict__ xb,
                                             unsigned short* __restrict__ Wt1,
                                             unsigned short* __restrict__ Wt2,
                                             unsigned short* __restrict__ Wt3,
                                             float* __restrict__ bs1, float* __restrict__ bs2,
                                             float* __restrict__ bnsum) {
    int blk = blockIdx.x, tid = threadIdx.x;
    if (blk < CAST_BLKS) {
        int i = blk * 256 + tid;
        float4 v = *(const float4*)(x + (size_t)i * 4);
        unsigned short u[4] = {f2bf(v.x), f2bf(v.y), f2bf(v.z), f2bf(v.w)};
        *(ushort4*)(xb + (size_t)i * 4) = *(ushort4*)u;
    } else if (blk < CAST_BLKS + 256) {
        int i = (blk - CAST_BLKS) * 256 + tid;  // [0, 65536)
        int kk = i & 511, n = i >> 9;           // coalesced stores along kk
        Wt1[n * 512 + kk] = f2bf(W1[kk * 128 + n]);
        Wt2[n * 512 + kk] = f2bf(W2[kk * 128 + n]);
    } else if (blk < CAST_BLKS + 320) {
        int i = (blk - CAST_BLKS - 256) * 256 + tid;  // [0, 16384)
        int kk = i & 127, n = i >> 7;
        Wt3[n * 128 + kk] = f2bf(l1W[kk * 128 + n]);
    } else {
        if (tid < 128) {
            bs1[tid] = b1[tid] + b1[128 + tid] + b1[256 + tid] + b1[384 + tid];
            bs2[tid] = b2[tid] + b2[128 + tid] + b2[256 + tid] + b2[384 + tid];
        }
        bnsum[tid] = 0.f;  // 256 floats
    }
}

// ---------------- pass A: bin edges into (chunk, range) fragment windows ----------------
// packed = src | dstlocal<<16 (src<50000 fits 16 bits, dstlocal 9 bits)
__global__ __launch_bounds__(256) void k_bin(const int* __restrict__ ei,
                                             int* __restrict__ frag,
                                             int* __restrict__ cntg) {
    int c = blockIdx.x, r = blockIdx.y;
    const int* srcp = ei + r * 2 * NE;
    const int* dstp = srcp + NE;
    __shared__ int bins[NRANGE * FCAP];  // 37.6 KB
    __shared__ int cnt[NRANGE];
    int tid = threadIdx.x;
    for (int i = tid; i < NRANGE; i += 256) cnt[i] = 0;
    __syncthreads();
    int e0 = c * CH, e1 = min(e0 + CH, NE);
    for (int e = e0 + tid; e < e1; e += 256) {
        int d = dstp[e];
        int s = srcp[e];
        int q = d >> 9;
        int pos = atomicAdd(&cnt[q], 1);
        if (pos < FCAP) bins[q * FCAP + pos] = s | ((d & 511) << 16);
    }
    __syncthreads();
    int w = tid >> 6, lane = tid & 63;
    for (int q = w; q < NRANGE; q += 4) {
        int k = min(cnt[q], FCAP);
        int gbase = ((r * NRANGE + q) * NCH + c) * FCAP;
        for (int i = lane; i < k; i += 64) frag[gbase + i] = bins[q * FCAP + i];
    }
    for (int q = tid; q < NRANGE; q += 256) cntg[(r * NRANGE + q) * NCH + c] = min(cnt[q], FCAP);
}

// ---------------- pass B: per (range, rel) counting-sort into CSR ----------------
__global__ __launch_bounds__(512) void k_sortb(const int* __restrict__ frag,
                                               const int* __restrict__ cntg,
                                               unsigned short* __restrict__ csr,
                                               int* __restrict__ rstart,
                                               int* __restrict__ rend,
                                               float* __restrict__ dinv) {
    int q = blockIdx.x, r = blockIdx.y;
    int blk = r * NRANGE + q;
    int n0 = q * RSZ;
    int nrows = min(RSZ, NN - n0);
    __shared__ int cnts[NCH], cbase[NCH];
    __shared__ int stage[BCAP];          // 24 KB
    __shared__ unsigned short csr_s[BCAP];
    __shared__ int hist[RSZ], off[RSZ], cnt2[RSZ];
    int tid = threadIdx.x;
    hist[tid] = 0;
    cnt2[tid] = 0;
    if (tid < NCH) cnts[tid] = cntg[blk * NCH + tid];
    __syncthreads();
    // exclusive scan of 128 chunk counts
    if (tid < NCH) cbase[tid] = cnts[tid];
    __syncthreads();
    for (int d = 1; d < NCH; d <<= 1) {
        int t = 0;
        if (tid < NCH && tid >= d) t = cbase[tid - d];
        __syncthreads();
        if (tid < NCH) cbase[tid] += t;
        __syncthreads();
    }
    if (tid < NCH) cbase[tid] -= cnts[tid];
    __syncthreads();
    int tot = cbase[NCH - 1] + cnts[NCH - 1];
    // parallel gather of all 128 fragment windows (4 threads per chunk)
    {
        int g = tid >> 2, l = tid & 3;
        int k = cnts[g], cb = cbase[g];
        int gbase = (blk * NCH + g) * FCAP;
        for (int i = l; i < k; i += 4)
            if (cb + i < BCAP) stage[cb + i] = frag[gbase + i];
    }
    __syncthreads();
    if (tot > BCAP) tot = BCAP;
    // histogram over dst-local
    for (int i = tid; i < tot; i += 512) atomicAdd(&hist[(stage[i] >> 16) & 511], 1);
    __syncthreads();
    int h = hist[tid];
    if (tid < nrows) dinv[r * NN + n0 + tid] = rsqrtf((float)(h + 1));  // +1 self loop
    // inclusive scan -> exclusive offsets
    off[tid] = h;
    __syncthreads();
    for (int d = 1; d < RSZ; d <<= 1) {
        int t = (tid >= d) ? off[tid - d] : 0;
        __syncthreads();
        off[tid] += t;
        __syncthreads();
    }
    int excl = off[tid] - h;
    __syncthreads();
    off[tid] = excl;
    int base = blk * BCAP;
    if (tid < nrows) {
        rstart[r * NN + n0 + tid] = base + excl;
        rend[r * NN + n0 + tid] = base + excl + h;
    }
    __syncthreads();
    // counting-sort into LDS
    for (int i = tid; i < tot; i += 512) {
        int v = stage[i];
        int dl = (v >> 16) & 511;
        int p = atomicAdd(&cnt2[dl], 1);
        csr_s[off[dl] + p] = (unsigned short)(v & 0xFFFF);
    }
    __syncthreads();
    // coalesced block-private write-out
    for (int i = tid; i < tot; i += 512) csr[base + i] = csr_s[i];
}

// ---------------- fill per-edge weights: wcsr[i] = dinv[r][csr[i]] ----------------
// Runs once (after sort); removes the per-edge dependent dinv gather from BOTH k_agg passes.
__global__ __launch_bounds__(256) void k_wei(const unsigned short* __restrict__ csr,
                                             const float* __restrict__ dinv,
                                             float* __restrict__ wcsr) {
    int gi = blockIdx.x * 256 + threadIdx.x;
    int r = gi / (NRANGE * BCAP);
    int s = csr[gi];                       // garbage in gaps is harmless (clamped, never read)
    wcsr[gi] = dinv[r * NN + min(s, NN - 1)];
}

// ---------------- per-(node,relation) gather aggregation, quarter-split ----------------
// Wave = one (node, rel). Lanes: quarter q=lane>>4 (edge slot), t=lane&15 (8-col group).
// Edge indices+weights are hoisted into registers with ONE coalesced 64-wide load, then
// distributed via shuffles -> the inner loop has NO dependent scalar gathers; 4 full-row
// (256B, short8/lane) loads per quarter issue back-to-back before any fma consumes them.
__global__ __launch_bounds__(256) void k_agg(const unsigned short* __restrict__ in,  // bf16 [NN][128]
                                             const unsigned short* __restrict__ csr,
                                             const float* __restrict__ wcsr,
                                             const int* __restrict__ rstart,
                                             const int* __restrict__ rend,
                                             const float* __restrict__ dinv,         // [NREL][NN]
                                             unsigned short* __restrict__ Acat) {    // bf16 [NN][512]
    int r = blockIdx.y;
    int wave = threadIdx.x >> 6, lane = threadIdx.x & 63;
    int n = blockIdx.x * 4 + wave;
    if (n >= NN) return;
    int nb = r * NN + n;
    int start = rstart[nb], end = rend[nb];
    int deg = end - start;
    int q = lane >> 4, t = lane & 15;
    const short8* in8 = (const short8*)in;  // row stride 16 (128 bf16)
    float a[8];
#pragma unroll
    for (int j = 0; j < 8; j++) a[j] = 0.f;
    for (int w0 = 0; w0 < deg; w0 += 64) {
        // cooperative window load: lane l holds edge (w0+l)'s src + weight
        int li = w0 + lane;
        int sv = 0;
        float wv = 0.f;
        if (li < deg) {
            sv = csr[start + li];
            wv = wcsr[start + li];
        }
        int cnt = min(deg - w0, 64);
        for (int b = 0; b < cnt; b += 16) {
            int e = b + q * 4;  // this quarter's 4 edges (invalid ones have wv=0, sv=0)
            int s0 = __shfl(sv, e + 0), s1 = __shfl(sv, e + 1);
            int s2 = __shfl(sv, e + 2), s3 = __shfl(sv, e + 3);
            float f0 = __shfl(wv, e + 0), f1 = __shfl(wv, e + 1);
            float f2 = __shfl(wv, e + 2), f3 = __shfl(wv, e + 3);
            short8 u0 = in8[s0 * 16 + t];
            short8 u1 = in8[s1 * 16 + t];
            short8 u2 = in8[s2 * 16 + t];
            short8 u3 = in8[s3 * 16 + t];
#pragma unroll
            for (int j = 0; j < 8; j++) a[j] = fmaf(bf2f((unsigned short)u0[j]), f0, a[j]);
#pragma unroll
            for (int j = 0; j < 8; j++) a[j] = fmaf(bf2f((unsigned short)u1[j]), f1, a[j]);
#pragma unroll
            for (int j = 0; j < 8; j++) a[j] = fmaf(bf2f((unsigned short)u2[j]), f2, a[j]);
#pragma unroll
            for (int j = 0; j < 8; j++) a[j] = fmaf(bf2f((unsigned short)u3[j]), f3, a[j]);
        }
    }
    // reduce the 4 quarters (lanes with equal t)
#pragma unroll
    for (int j = 0; j < 8; j++) {
        a[j] += __shfl_xor(a[j], 16);
        a[j] += __shfl_xor(a[j], 32);
    }
    if (q == 0) {
        // self loop + dst scale + write (16 lanes x 16B = coalesced 256B row)
        float wn = dinv[nb];
        short8 us = in8[n * 16 + t];
        unsigned short ob[8];
#pragma unroll
        for (int j = 0; j < 8; j++)
            ob[j] = f2bf(wn * fmaf(bf2f((unsigned short)us[j]), wn, a[j]));
        *(short8*)(Acat + (size_t)n * 512 + r * 128 + t * 8) = *(short8*)ob;
    }
}

// ---------------- MFMA GEMM: C[NN][128] = relu(A[NN][K] @ W[K][128] + bias) (bf16 in/out) ----------------
template <int K, bool STATS>
__global__ __launch_bounds__(256) void k_mm(const unsigned short* __restrict__ A,
                                            const unsigned short* __restrict__ Bt,
                                            const float* __restrict__ bias,
                                            unsigned short* __restrict__ C,
                                            float* __restrict__ bnsum) {
    int tid = threadIdx.x;
    int w = tid >> 6, lane = tid & 63;
    int ln = lane & 15, quad = lane >> 4;
    int mwave = blockIdx.x * 256 + w * 64;

    f32x4 acc[4][8];
#pragma unroll
    for (int a = 0; a < 4; a++)
#pragma unroll
        for (int b = 0; b < 8; b++) acc[a][b] = (f32x4){0.f, 0.f, 0.f, 0.f};

    size_t arow[4];
#pragma unroll
    for (int mf = 0; mf < 4; mf++) {
        int m = mwave + mf * 16 + ln;
        arow[mf] = (size_t)min(m, NN - 1) * K;  // clamp; garbage rows guarded at store
    }
    size_t brow[8];
#pragma unroll
    for (int nf = 0; nf < 8; nf++) brow[nf] = (size_t)(nf * 16 + ln) * K;

    for (int k0 = 0; k0 < K; k0 += 32) {
        int kof = k0 + quad * 8;
        short8 af[4], bf[8];
#pragma unroll
        for (int mf = 0; mf < 4; mf++) af[mf] = *(const short8*)(A + arow[mf] + kof);
#pragma unroll
        for (int nf = 0; nf < 8; nf++) bf[nf] = *(const short8*)(Bt + brow[nf] + kof);
#pragma unroll
        for (int mf = 0; mf < 4; mf++)
#pragma unroll
            for (int nf = 0; nf < 8; nf++)
                acc[mf][nf] = __builtin_amdgcn_mfma_f32_16x16x32_bf16(af[mf], bf[nf], acc[mf][nf], 0, 0, 0);
    }

    float bs[8];
#pragma unroll
    for (int nf = 0; nf < 8; nf++) bs[nf] = bias[nf * 16 + ln];
    float sn[8], qn[8];
#pragma unroll
    for (int nf = 0; nf < 8; nf++) { sn[nf] = 0.f; qn[nf] = 0.f; }

#pragma unroll
    for (int mf = 0; mf < 4; mf++)
#pragma unroll
        for (int nf = 0; nf < 8; nf++)
#pragma unroll
            for (int rg = 0; rg < 4; rg++) {
                int m = mwave + mf * 16 + quad * 4 + rg;
                if (m < NN) {
                    float v = fmaxf(acc[mf][nf][rg] + bs[nf], 0.f);
                    if (STATS) { sn[nf] += v; qn[nf] += v * v; }
                    C[(size_t)m * 128 + nf * 16 + ln] = f2bf(v);
                }
            }

    if (STATS) {
#pragma unroll
        for (int nf = 0; nf < 8; nf++) {
            float s = sn[nf], q = qn[nf];
            s += __shfl_xor(s, 16); s += __shfl_xor(s, 32);
            q += __shfl_xor(q, 16); q += __shfl_xor(q, 32);
            if (quad == 0) {
                unsafeAtomicAdd(&bnsum[nf * 16 + ln], s);
                unsafeAtomicAdd(&bnsum[128 + nf * 16 + ln], q);
            }
        }
    }
}

// ---------------- final: BN affine from bnsum + relu(BN(R2)@l1W+l1b)@l2W+l2b ----------------
__global__ __launch_bounds__(256) void k_final(const unsigned short* __restrict__ R2,
                                               const float* __restrict__ bnsum,
                                               const float* __restrict__ gamma,
                                               const float* __restrict__ beta,
                                               const unsigned short* __restrict__ Wt3,
                                               const float* __restrict__ l1b,
                                               const float* __restrict__ l2W,
                                               const float* __restrict__ l2b,
                                               float* __restrict__ out) {
    __shared__ float bnp_s[256];
    int tid = threadIdx.x;
    if (tid < 128) {
        float mean = bnsum[tid] / (float)NN;
        float var = bnsum[128 + tid] / (float)NN - mean * mean;
        float sc = gamma[tid] * rsqrtf(var + BN_EPS);
        bnp_s[tid] = sc;
        bnp_s[128 + tid] = beta[tid] - mean * sc;
    }
    __syncthreads();
    int w = tid >> 6, lane = tid & 63;
    int ln = lane & 15, quad = lane >> 4;
    int mwave = blockIdx.x * 256 + w * 64;

    f32x4 acc[4][8];
#pragma unroll
    for (int a = 0; a < 4; a++)
#pragma unroll
        for (int b = 0; b < 8; b++) acc[a][b] = (f32x4){0.f, 0.f, 0.f, 0.f};

    size_t arow[4];
#pragma unroll
    for (int mf = 0; mf < 4; mf++) {
        int m = mwave + mf * 16 + ln;
        arow[mf] = (size_t)min(m, NN - 1) * 128;
    }
    size_t brow[8];
#pragma unroll
    for (int nf = 0; nf < 8; nf++) brow[nf] = (size_t)(nf * 16 + ln) * 128;

    for (int k0 = 0; k0 < 128; k0 += 32) {
        int kof = k0 + quad * 8;
        float scv[8], shv[8];
#pragma unroll
        for (int j = 0; j < 8; j++) {
            scv[j] = bnp_s[kof + j];
            shv[j] = bnp_s[128 + kof + j];
        }
        short8 af[4], bf[8];
#pragma unroll
        for (int mf = 0; mf < 4; mf++) {
            short8 rv = *(const short8*)(R2 + arow[mf] + kof);
            unsigned short ab[8];
#pragma unroll
            for (int j = 0; j < 8; j++)
                ab[j] = f2bf(bf2f((unsigned short)rv[j]) * scv[j] + shv[j]);
            af[mf] = *(short8*)ab;
        }
#pragma unroll
        for (int nf = 0; nf < 8; nf++) bf[nf] = *(const short8*)(Wt3 + brow[nf] + kof);
#pragma unroll
        for (int mf = 0; mf < 4; mf++)
#pragma unroll
            for (int nf = 0; nf < 8; nf++)
                acc[mf][nf] = __builtin_amdgcn_mfma_f32_16x16x32_bf16(af[mf], bf[nf], acc[mf][nf], 0, 0, 0);
    }

    float b1v[8], w0[8], w1[8];
#pragma unroll
    for (int nf = 0; nf < 8; nf++) {
        int n = nf * 16 + ln;
        b1v[nf] = l1b[n];
        w0[nf] = l2W[n * 2];
        w1[nf] = l2W[n * 2 + 1];
    }
    float ob0 = l2b[0], ob1 = l2b[1];
#pragma unroll
    for (int mf = 0; mf < 4; mf++)
#pragma unroll
        for (int rg = 0; rg < 4; rg++) {
            float p0 = 0.f, p1 = 0.f;
#pragma unroll
            for (int nf = 0; nf < 8; nf++) {
                float y = fmaxf(acc[mf][nf][rg] + b1v[nf], 0.f);
                p0 += y * w0[nf];
                p1 += y * w1[nf];
            }
            p0 += __shfl_xor(p0, 1); p0 += __shfl_xor(p0, 2);
            p0 += __shfl_xor(p0, 4); p0 += __shfl_xor(p0, 8);
            p1 += __shfl_xor(p1, 1); p1 += __shfl_xor(p1, 2);
            p1 += __shfl_xor(p1, 4); p1 += __shfl_xor(p1, 8);
            int m = mwave + mf * 16 + quad * 4 + rg;
            if (ln == 0 && m < NN) {
                out[(size_t)m * 2 + 0] = p0 + ob0;
                out[(size_t)m * 2 + 1] = p1 + ob1;
            }
        }
}

extern "C" void kernel_launch(void* const* d_in, const int* in_sizes, int n_in,
                              void* d_out, int out_size, void* d_ws, size_t ws_size,
                              hipStream_t stream) {
    const float* x = (const float*)d_in[0];
    const int* ei = (const int*)d_in[1];
    const float* W1 = (const float*)d_in[2];
    const float* b1 = (const float*)d_in[3];
    const float* W2 = (const float*)d_in[4];
    const float* b2 = (const float*)d_in[5];
    const float* gamma = (const float*)d_in[6];
    const float* beta = (const float*)d_in[7];
    const float* l1W = (const float*)d_in[8];
    const float* l1b = (const float*)d_in[9];
    const float* l2W = (const float*)d_in[10];
    const float* l2b = (const float*)d_in[11];
    float* out = (float*)d_out;

    char* ws = (char*)d_ws;
    size_t off = 0;
    auto alloc = [&](size_t bytes) {
        void* p = ws + off;
        off += (bytes + 255) & ~(size_t)255;
        return p;
    };
    float* dinv = (float*)alloc((size_t)NREL * NN * sizeof(float));
    int* rstart = (int*)alloc((size_t)NREL * NN * sizeof(int));
    int* rend = (int*)alloc((size_t)NREL * NN * sizeof(int));
    unsigned short* csr = (unsigned short*)alloc((size_t)NBK * BCAP * 2);            // 4.8 MB
    unsigned short* xb = (unsigned short*)alloc((size_t)NN * D * 2);                 // 12.8 MB
    unsigned short* Acat = (unsigned short*)alloc((size_t)NN * 512 * 2);             // 51.2 MB
    unsigned short* h1b = (unsigned short*)alloc((size_t)NN * D * 2);                // 12.8 MB
    unsigned short* R2b = (unsigned short*)alloc((size_t)NN * D * 2);                // 12.8 MB
    unsigned short* Wt1 = (unsigned short*)alloc(128 * 512 * 2);
    unsigned short* Wt2 = (unsigned short*)alloc(128 * 512 * 2);
    unsigned short* Wt3 = (unsigned short*)alloc(128 * 128 * 2);
    float* bs1 = (float*)alloc(128 * sizeof(float));
    float* bs2 = (float*)alloc(128 * sizeof(float));
    float* bnsum = (float*)alloc(256 * sizeof(float));

    // frag/cntg alias Acat's storage (dead until k_agg writes it, after k_sortb completes)
    int* frag = (int*)Acat;                                       // 19.3 MB
    int* cntg = frag + (size_t)NREL * NRANGE * NCH * FCAP;        // 0.2 MB
    // wcsr (9.63 MB f32) aliases R2b: R2b is first written by k_mm<512,true>, which is
    // stream-ordered AFTER the last wcsr read (k_agg #2). No workspace growth.
    float* wcsr = (float*)R2b;

    k_pre<<<CAST_BLKS + 321, 256, 0, stream>>>(x, W1, W2, l1W, b1, b2, xb, Wt1, Wt2, Wt3,
                                               bs1, bs2, bnsum);
    dim3 bgrid(NCH, NREL);
    k_bin<<<bgrid, 256, 0, stream>>>(ei, frag, cntg);
    dim3 sgrid(NRANGE, NREL);
    k_sortb<<<sgrid, 512, 0, stream>>>(frag, cntg, csr, rstart, rend, dinv);
    k_wei<<<(NBK * BCAP) / 256, 256, 0, stream>>>(csr, dinv, wcsr);

    dim3 agrid((NN + 3) / 4, NREL);
    // layer 1: aggregate x per relation -> Acat (concat), then one K=512 GEMM
    k_agg<<<agrid, 256, 0, stream>>>(xb, csr, wcsr, rstart, rend, dinv, Acat);
    k_mm<512, false><<<(NN + 255) / 256, 256, 0, stream>>>(Acat, Wt1, bs1, h1b, nullptr);
    // layer 2
    k_agg<<<agrid, 256, 0, stream>>>(h1b, csr, wcsr, rstart, rend, dinv, Acat);
    k_mm<512, true><<<(NN + 255) / 256, 256, 0, stream>>>(Acat, Wt2, bs2, R2b, bnsum);
    // fused BN + MLP head
    k_final<<<(NN + 255) / 256, 256, 0, stream>>>(R2b, bnsum, gamma, beta, Wt3, l1b, l2W, l2b, out);
}

// Round 2
// 386.975 us; speedup vs baseline: 1.1080x; 1.0233x over previous
//
#include <hip/hip_runtime.h>
#include <math.h>

#define NN 50000
#define NE 500000
#define NREL 4
#define D 128
#define RSZ 512                 // dst-range size (one bin)
#define NRANGE 98               // ceil(NN/512)
#define NBK (NREL * NRANGE)     // 392 sort blocks
#define BCAP 6144               // per-(range,rel) csr capacity (mean 5120, +14 sigma)
#define NCH 128                 // edge chunks per relation
#define CH 3907                 // edges per chunk (128*3907 >= 500000)
#define FCAP 96                 // frag capacity per (chunk,bin): mean 40, +9 sigma
#define CAST_BLKS 6250          // NN*D/4/256
static constexpr float BN_EPS = 1e-5f;

typedef __attribute__((ext_vector_type(8))) _Float16 half8;
typedef __attribute__((ext_vector_type(4))) float f32x4;

__device__ __forceinline__ unsigned short f2h_bits(float f) {
    _Float16 h = (_Float16)f;  // v_cvt_f16_f32 (RTNE)
    return __builtin_bit_cast(unsigned short, h);
}

// ---------------- fused prologue: cast x->f16, weight transpose+cast, bias sums, bnsum zero ----
__global__ __launch_bounds__(256) void k_pre(const float* __restrict__ x,
                                             const float* __restrict__ W1, const float* __restrict__ W2,
                                             const float* __restrict__ l1W, const float* __restrict__ b1,
                                             const float* __restrict__ b2,
                                             unsigned short* __restrict__ xb,
                                             unsigned short* __restrict__ Wt1,
                                             unsigned short* __restrict__ Wt2,
                                             unsigned short* __restrict__ Wt3,
                                             float* __restrict__ bs1, float* __restrict__ bs2,
                                             float* __restrict__ bnsum) {
    int blk = blockIdx.x, tid = threadIdx.x;
    if (blk < CAST_BLKS) {
        int i = blk * 256 + tid;
        float4 v = *(const float4*)(x + (size_t)i * 4);
        unsigned short u[4] = {f2h_bits(v.x), f2h_bits(v.y), f2h_bits(v.z), f2h_bits(v.w)};
        *(ushort4*)(xb + (size_t)i * 4) = *(ushort4*)u;
    } else if (blk < CAST_BLKS + 256) {
        int i = (blk - CAST_BLKS) * 256 + tid;  // [0, 65536)
        int kk = i & 511, n = i >> 9;           // coalesced stores along kk
        Wt1[n * 512 + kk] = f2h_bits(W1[kk * 128 + n]);
        Wt2[n * 512 + kk] = f2h_bits(W2[kk * 128 + n]);
    } else if (blk < CAST_BLKS + 320) {
        int i = (blk - CAST_BLKS - 256) * 256 + tid;  // [0, 16384)
        int kk = i & 127, n = i >> 7;
        Wt3[n * 128 + kk] = f2h_bits(l1W[kk * 128 + n]);
    } else {
        if (tid < 128) {
            bs1[tid] = b1[tid] + b1[128 + tid] + b1[256 + tid] + b1[384 + tid];
            bs2[tid] = b2[tid] + b2[128 + tid] + b2[256 + tid] + b2[384 + tid];
        }
        bnsum[tid] = 0.f;  // 256 floats
    }
}

// ---------------- pass A: bin edges into (chunk, range) fragment windows ----------------
// packed = src | dstlocal<<16 (src<50000 fits 16 bits, dstlocal 9 bits)
__global__ __launch_bounds__(256) void k_bin(const int* __restrict__ ei,
                                             int* __restrict__ frag,
                                             int* __restrict__ cntg) {
    int c = blockIdx.x, r = blockIdx.y;
    const int* srcp = ei + r * 2 * NE;
    const int* dstp = srcp + NE;
    __shared__ int bins[NRANGE * FCAP];  // 37.6 KB
    __shared__ int cnt[NRANGE];
    int tid = threadIdx.x;
    for (int i = tid; i < NRANGE; i += 256) cnt[i] = 0;
    __syncthreads();
    int e0 = c * CH, e1 = min(e0 + CH, NE);
    for (int e = e0 + tid; e < e1; e += 256) {
        int d = dstp[e];
        int s = srcp[e];
        int q = d >> 9;
        int pos = atomicAdd(&cnt[q], 1);
        if (pos < FCAP) bins[q * FCAP + pos] = s | ((d & 511) << 16);
    }
    __syncthreads();
    int w = tid >> 6, lane = tid & 63;
    for (int q = w; q < NRANGE; q += 4) {
        int k = min(cnt[q], FCAP);
        int gbase = ((r * NRANGE + q) * NCH + c) * FCAP;
        for (int i = lane; i < k; i += 64) frag[gbase + i] = bins[q * FCAP + i];
    }
    for (int q = tid; q < NRANGE; q += 256) cntg[(r * NRANGE + q) * NCH + c] = min(cnt[q], FCAP);
}

// ---------------- pass B: per (range, rel) counting-sort into CSR ----------------
__global__ __launch_bounds__(512) void k_sortb(const int* __restrict__ frag,
                                               const int* __restrict__ cntg,
                                               unsigned short* __restrict__ csr,
                                               int* __restrict__ rstart,
                                               int* __restrict__ rend,
                                               float* __restrict__ dinv) {
    int q = blockIdx.x, r = blockIdx.y;
    int blk = r * NRANGE + q;
    int n0 = q * RSZ;
    int nrows = min(RSZ, NN - n0);
    __shared__ int cnts[NCH], cbase[NCH];
    __shared__ int stage[BCAP];          // 24 KB
    __shared__ unsigned short csr_s[BCAP];
    __shared__ int hist[RSZ], off[RSZ], cnt2[RSZ];
    int tid = threadIdx.x;
    hist[tid] = 0;
    cnt2[tid] = 0;
    if (tid < NCH) cnts[tid] = cntg[blk * NCH + tid];
    __syncthreads();
    // exclusive scan of 128 chunk counts
    if (tid < NCH) cbase[tid] = cnts[tid];
    __syncthreads();
    for (int d = 1; d < NCH; d <<= 1) {
        int t = 0;
        if (tid < NCH && tid >= d) t = cbase[tid - d];
        __syncthreads();
        if (tid < NCH) cbase[tid] += t;
        __syncthreads();
    }
    if (tid < NCH) cbase[tid] -= cnts[tid];
    __syncthreads();
    int tot = cbase[NCH - 1] + cnts[NCH - 1];
    // parallel gather of all 128 fragment windows (4 threads per chunk)
    {
        int g = tid >> 2, l = tid & 3;
        int k = cnts[g], cb = cbase[g];
        int gbase = (blk * NCH + g) * FCAP;
        for (int i = l; i < k; i += 4)
            if (cb + i < BCAP) stage[cb + i] = frag[gbase + i];
    }
    __syncthreads();
    if (tot > BCAP) tot = BCAP;
    // histogram over dst-local
    for (int i = tid; i < tot; i += 512) atomicAdd(&hist[(stage[i] >> 16) & 511], 1);
    __syncthreads();
    int h = hist[tid];
    if (tid < nrows) dinv[r * NN + n0 + tid] = rsqrtf((float)(h + 1));  // +1 self loop
    // inclusive scan -> exclusive offsets
    off[tid] = h;
    __syncthreads();
    for (int d = 1; d < RSZ; d <<= 1) {
        int t = (tid >= d) ? off[tid - d] : 0;
        __syncthreads();
        off[tid] += t;
        __syncthreads();
    }
    int excl = off[tid] - h;
    __syncthreads();
    off[tid] = excl;
    int base = blk * BCAP;
    if (tid < nrows) {
        rstart[r * NN + n0 + tid] = base + excl;
        rend[r * NN + n0 + tid] = base + excl + h;
    }
    __syncthreads();
    // counting-sort into LDS
    for (int i = tid; i < tot; i += 512) {
        int v = stage[i];
        int dl = (v >> 16) & 511;
        int p = atomicAdd(&cnt2[dl], 1);
        csr_s[off[dl] + p] = (unsigned short)(v & 0xFFFF);
    }
    __syncthreads();
    // coalesced block-private write-out
    for (int i = tid; i < tot; i += 512) csr[base + i] = csr_s[i];
}

// ---------------- fill per-edge weights: wcsr[i] = dinv[r][csr[i]] ----------------
// Runs once (after sort); removes the per-edge dependent dinv gather from BOTH k_agg passes.
__global__ __launch_bounds__(256) void k_wei(const unsigned short* __restrict__ csr,
                                             const float* __restrict__ dinv,
                                             float* __restrict__ wcsr) {
    int gi = blockIdx.x * 256 + threadIdx.x;
    int r = gi / (NRANGE * BCAP);
    int s = csr[gi];                       // garbage in gaps is harmless (clamped, never read)
    wcsr[gi] = dinv[r * NN + min(s, NN - 1)];
}

// ---------------- per-(node,relation) gather aggregation, quarter-split ----------------
// Wave = one (node, rel). Lanes: quarter q=lane>>4 (edge slot), t=lane&15 (8-col group).
// Edge indices+weights hoisted via ONE coalesced 64-wide load + shuffles. Features are f16:
// fmaf((float)h, w, a) forms v_fma_mix_f32 (f16 operand consumed directly, no cvt) -> inner
// VALU per edge halves vs bf16 (which needed an explicit shift-cvt per element).
// Self-row + dinv loads hoisted to the top (independent of the CSR chain).
__global__ __launch_bounds__(256) void k_agg(const unsigned short* __restrict__ in,  // f16 [NN][128]
                                             const unsigned short* __restrict__ csr,
                                             const float* __restrict__ wcsr,
                                             const int* __restrict__ rstart,
                                             const int* __restrict__ rend,
                                             const float* __restrict__ dinv,         // [NREL][NN]
                                             unsigned short* __restrict__ Acat) {    // f16 [NN][512]
    int r = blockIdx.y;
    int wave = threadIdx.x >> 6, lane = threadIdx.x & 63;
    int n = blockIdx.x * 4 + wave;
    if (n >= NN) return;
    int nb = r * NN + n;
    int q = lane >> 4, t = lane & 15;
    const half8* in8 = (const half8*)in;  // row stride 16 (128 f16)
    // hoisted epilogue inputs (independent of CSR chain -> overlap with everything)
    half8 us = in8[(size_t)n * 16 + t];
    float wn = dinv[nb];
    int start = rstart[nb], end = rend[nb];
    int deg = end - start;
    float a[8];
#pragma unroll
    for (int j = 0; j < 8; j++) a[j] = 0.f;
    for (int w0 = 0; w0 < deg; w0 += 64) {
        // cooperative window load: lane l holds edge (w0+l)'s src + weight
        int li = w0 + lane;
        int sv = 0;
        float wv = 0.f;
        if (li < deg) {
            sv = csr[start + li];
            wv = wcsr[start + li];
        }
        int cnt = min(deg - w0, 64);
        for (int b = 0; b < cnt; b += 16) {
            int e = b + q * 4;  // this quarter's 4 edges (invalid ones have wv=0, sv=0)
            int s0 = __shfl(sv, e + 0), s1 = __shfl(sv, e + 1);
            int s2 = __shfl(sv, e + 2), s3 = __shfl(sv, e + 3);
            float f0 = __shfl(wv, e + 0), f1 = __shfl(wv, e + 1);
            float f2 = __shfl(wv, e + 2), f3 = __shfl(wv, e + 3);
            half8 u0 = in8[s0 * 16 + t];
            half8 u1 = in8[s1 * 16 + t];
            half8 u2 = in8[s2 * 16 + t];
            half8 u3 = in8[s3 * 16 + t];
#pragma unroll
            for (int j = 0; j < 8; j++) a[j] = fmaf((float)u0[j], f0, a[j]);
#pragma unroll
            for (int j = 0; j < 8; j++) a[j] = fmaf((float)u1[j], f1, a[j]);
#pragma unroll
            for (int j = 0; j < 8; j++) a[j] = fmaf((float)u2[j], f2, a[j]);
#pragma unroll
            for (int j = 0; j < 8; j++) a[j] = fmaf((float)u3[j], f3, a[j]);
        }
    }
    // reduce the 4 quarters (lanes with equal t)
#pragma unroll
    for (int j = 0; j < 8; j++) {
        a[j] += __shfl_xor(a[j], 16);
        a[j] += __shfl_xor(a[j], 32);
    }
    if (q == 0) {
        // self loop + dst scale + write (16 lanes x 16B = coalesced 256B row)
        _Float16 ob[8];
#pragma unroll
        for (int j = 0; j < 8; j++)
            ob[j] = (_Float16)(wn * fmaf((float)us[j], wn, a[j]));
        *(half8*)(Acat + (size_t)n * 512 + r * 128 + t * 8) = *(half8*)ob;
    }
}

// ---------------- MFMA GEMM: C[NN][128] = relu(A[NN][K] @ W[K][128] + bias) (f16 in/out) ----------------
template <int K, bool STATS>
__global__ __launch_bounds__(256) void k_mm(const unsigned short* __restrict__ A,
                                            const unsigned short* __restrict__ Bt,
                                            const float* __restrict__ bias,
                                            unsigned short* __restrict__ C,
                                            float* __restrict__ bnsum) {
    int tid = threadIdx.x;
    int w = tid >> 6, lane = tid & 63;
    int ln = lane & 15, quad = lane >> 4;
    int mwave = blockIdx.x * 256 + w * 64;

    f32x4 acc[4][8];
#pragma unroll
    for (int a = 0; a < 4; a++)
#pragma unroll
        for (int b = 0; b < 8; b++) acc[a][b] = (f32x4){0.f, 0.f, 0.f, 0.f};

    size_t arow[4];
#pragma unroll
    for (int mf = 0; mf < 4; mf++) {
        int m = mwave + mf * 16 + ln;
        arow[mf] = (size_t)min(m, NN - 1) * K;  // clamp; garbage rows guarded at store
    }
    size_t brow[8];
#pragma unroll
    for (int nf = 0; nf < 8; nf++) brow[nf] = (size_t)(nf * 16 + ln) * K;

    for (int k0 = 0; k0 < K; k0 += 32) {
        int kof = k0 + quad * 8;
        half8 af[4], bf[8];
#pragma unroll
        for (int mf = 0; mf < 4; mf++) af[mf] = *(const half8*)(A + arow[mf] + kof);
#pragma unroll
        for (int nf = 0; nf < 8; nf++) bf[nf] = *(const half8*)(Bt + brow[nf] + kof);
#pragma unroll
        for (int mf = 0; mf < 4; mf++)
#pragma unroll
            for (int nf = 0; nf < 8; nf++)
                acc[mf][nf] = __builtin_amdgcn_mfma_f32_16x16x32_f16(af[mf], bf[nf], acc[mf][nf], 0, 0, 0);
    }

    float bs[8];
#pragma unroll
    for (int nf = 0; nf < 8; nf++) bs[nf] = bias[nf * 16 + ln];
    float sn[8], qn[8];
#pragma unroll
    for (int nf = 0; nf < 8; nf++) { sn[nf] = 0.f; qn[nf] = 0.f; }

#pragma unroll
    for (int mf = 0; mf < 4; mf++)
#pragma unroll
        for (int nf = 0; nf < 8; nf++)
#pragma unroll
            for (int rg = 0; rg < 4; rg++) {
                int m = mwave + mf * 16 + quad * 4 + rg;
                if (m < NN) {
                    float v = fmaxf(acc[mf][nf][rg] + bs[nf], 0.f);
                    if (STATS) { sn[nf] += v; qn[nf] += v * v; }
                    C[(size_t)m * 128 + nf * 16 + ln] = f2h_bits(v);
                }
            }

    if (STATS) {
#pragma unroll
        for (int nf = 0; nf < 8; nf++) {
            float s = sn[nf], q = qn[nf];
            s += __shfl_xor(s, 16); s += __shfl_xor(s, 32);
            q += __shfl_xor(q, 16); q += __shfl_xor(q, 32);
            if (quad == 0) {
                unsafeAtomicAdd(&bnsum[nf * 16 + ln], s);
                unsafeAtomicAdd(&bnsum[128 + nf * 16 + ln], q);
            }
        }
    }
}

// ---------------- final: BN affine from bnsum + relu(BN(R2)@l1W+l1b)@l2W+l2b ----------------
__global__ __launch_bounds__(256) void k_final(const unsigned short* __restrict__ R2,
                                               const float* __restrict__ bnsum,
                                               const float* __restrict__ gamma,
                                               const float* __restrict__ beta,
                                               const unsigned short* __restrict__ Wt3,
                                               const float* __restrict__ l1b,
                                               const float* __restrict__ l2W,
                                               const float* __restrict__ l2b,
                                               float* __restrict__ out) {
    __shared__ float bnp_s[256];
    int tid = threadIdx.x;
    if (tid < 128) {
        float mean = bnsum[tid] / (float)NN;
        float var = bnsum[128 + tid] / (float)NN - mean * mean;
        float sc = gamma[tid] * rsqrtf(var + BN_EPS);
        bnp_s[tid] = sc;
        bnp_s[128 + tid] = beta[tid] - mean * sc;
    }
    __syncthreads();
    int w = tid >> 6, lane = tid & 63;
    int ln = lane & 15, quad = lane >> 4;
    int mwave = blockIdx.x * 256 + w * 64;

    f32x4 acc[4][8];
#pragma unroll
    for (int a = 0; a < 4; a++)
#pragma unroll
        for (int b = 0; b < 8; b++) acc[a][b] = (f32x4){0.f, 0.f, 0.f, 0.f};

    size_t arow[4];
#pragma unroll
    for (int mf = 0; mf < 4; mf++) {
        int m = mwave + mf * 16 + ln;
        arow[mf] = (size_t)min(m, NN - 1) * 128;
    }
    size_t brow[8];
#pragma unroll
    for (int nf = 0; nf < 8; nf++) brow[nf] = (size_t)(nf * 16 + ln) * 128;

    for (int k0 = 0; k0 < 128; k0 += 32) {
        int kof = k0 + quad * 8;
        float scv[8], shv[8];
#pragma unroll
        for (int j = 0; j < 8; j++) {
            scv[j] = bnp_s[kof + j];
            shv[j] = bnp_s[128 + kof + j];
        }
        half8 af[4], bf[8];
#pragma unroll
        for (int mf = 0; mf < 4; mf++) {
            half8 rv = *(const half8*)(R2 + arow[mf] + kof);
            _Float16 ab[8];
#pragma unroll
            for (int j = 0; j < 8; j++)
                ab[j] = (_Float16)(fmaf((float)rv[j], scv[j], shv[j]));
            af[mf] = *(half8*)ab;
        }
#pragma unroll
        for (int nf = 0; nf < 8; nf++) bf[nf] = *(const half8*)(Wt3 + brow[nf] + kof);
#pragma unroll
        for (int mf = 0; mf < 4; mf++)
#pragma unroll
            for (int nf = 0; nf < 8; nf++)
                acc[mf][nf] = __builtin_amdgcn_mfma_f32_16x16x32_f16(af[mf], bf[nf], acc[mf][nf], 0, 0, 0);
    }

    float b1v[8], w0[8], w1[8];
#pragma unroll
    for (int nf = 0; nf < 8; nf++) {
        int n = nf * 16 + ln;
        b1v[nf] = l1b[n];
        w0[nf] = l2W[n * 2];
        w1[nf] = l2W[n * 2 + 1];
    }
    float ob0 = l2b[0], ob1 = l2b[1];
#pragma unroll
    for (int mf = 0; mf < 4; mf++)
#pragma unroll
        for (int rg = 0; rg < 4; rg++) {
            float p0 = 0.f, p1 = 0.f;
#pragma unroll
            for (int nf = 0; nf < 8; nf++) {
                float y = fmaxf(acc[mf][nf][rg] + b1v[nf], 0.f);
                p0 += y * w0[nf];
                p1 += y * w1[nf];
            }
            p0 += __shfl_xor(p0, 1); p0 += __shfl_xor(p0, 2);
            p0 += __shfl_xor(p0, 4); p0 += __shfl_xor(p0, 8);
            p1 += __shfl_xor(p1, 1); p1 += __shfl_xor(p1, 2);
            p1 += __shfl_xor(p1, 4); p1 += __shfl_xor(p1, 8);
            int m = mwave + mf * 16 + quad * 4 + rg;
            if (ln == 0 && m < NN) {
                out[(size_t)m * 2 + 0] = p0 + ob0;
                out[(size_t)m * 2 + 1] = p1 + ob1;
            }
        }
}

extern "C" void kernel_launch(void* const* d_in, const int* in_sizes, int n_in,
                              void* d_out, int out_size, void* d_ws, size_t ws_size,
                              hipStream_t stream) {
    const float* x = (const float*)d_in[0];
    const int* ei = (const int*)d_in[1];
    const float* W1 = (const float*)d_in[2];
    const float* b1 = (const float*)d_in[3];
    const float* W2 = (const float*)d_in[4];
    const float* b2 = (const float*)d_in[5];
    const float* gamma = (const float*)d_in[6];
    const float* beta = (const float*)d_in[7];
    const float* l1W = (const float*)d_in[8];
    const float* l1b = (const float*)d_in[9];
    const float* l2W = (const float*)d_in[10];
    const float* l2b = (const float*)d_in[11];
    float* out = (float*)d_out;

    char* ws = (char*)d_ws;
    size_t off = 0;
    auto alloc = [&](size_t bytes) {
        void* p = ws + off;
        off += (bytes + 255) & ~(size_t)255;
        return p;
    };
    float* dinv = (float*)alloc((size_t)NREL * NN * sizeof(float));
    int* rstart = (int*)alloc((size_t)NREL * NN * sizeof(int));
    int* rend = (int*)alloc((size_t)NREL * NN * sizeof(int));
    unsigned short* csr = (unsigned short*)alloc((size_t)NBK * BCAP * 2);            // 4.8 MB
    unsigned short* xb = (unsigned short*)alloc((size_t)NN * D * 2);                 // 12.8 MB
    unsigned short* Acat = (unsigned short*)alloc((size_t)NN * 512 * 2);             // 51.2 MB
    unsigned short* h1b = (unsigned short*)alloc((size_t)NN * D * 2);                // 12.8 MB
    unsigned short* R2b = (unsigned short*)alloc((size_t)NN * D * 2);                // 12.8 MB
    unsigned short* Wt1 = (unsigned short*)alloc(128 * 512 * 2);
    unsigned short* Wt2 = (unsigned short*)alloc(128 * 512 * 2);
    unsigned short* Wt3 = (unsigned short*)alloc(128 * 128 * 2);
    float* bs1 = (float*)alloc(128 * sizeof(float));
    float* bs2 = (float*)alloc(128 * sizeof(float));
    float* bnsum = (float*)alloc(256 * sizeof(float));

    // frag/cntg alias Acat's storage (dead until k_agg writes it, after k_sortb completes)
    int* frag = (int*)Acat;                                       // 19.3 MB
    int* cntg = frag + (size_t)NREL * NRANGE * NCH * FCAP;        // 0.2 MB
    // wcsr (9.63 MB f32) aliases R2b: R2b is first written by k_mm<512,true>, which is
    // stream-ordered AFTER the last wcsr read (k_agg #2). No workspace growth.
    float* wcsr = (float*)R2b;

    k_pre<<<CAST_BLKS + 321, 256, 0, stream>>>(x, W1, W2, l1W, b1, b2, xb, Wt1, Wt2, Wt3,
                                               bs1, bs2, bnsum);
    dim3 bgrid(NCH, NREL);
    k_bin<<<bgrid, 256, 0, stream>>>(ei, frag, cntg);
    dim3 sgrid(NRANGE, NREL);
    k_sortb<<<sgrid, 512, 0, stream>>>(frag, cntg, csr, rstart, rend, dinv);
    k_wei<<<(NBK * BCAP) / 256, 256, 0, stream>>>(csr, dinv, wcsr);

    dim3 agrid((NN + 3) / 4, NREL);
    // layer 1: aggregate x per relation -> Acat (concat), then one K=512 GEMM
    k_agg<<<agrid, 256, 0, stream>>>(xb, csr, wcsr, rstart, rend, dinv, Acat);
    k_mm<512, false><<<(NN + 255) / 256, 256, 0, stream>>>(Acat, Wt1, bs1, h1b, nullptr);
    // layer 2
    k_agg<<<agrid, 256, 0, stream>>>(h1b, csr, wcsr, rstart, rend, dinv, Acat);
    k_mm<512, true><<<(NN + 255) / 256, 256, 0, stream>>>(Acat, Wt2, bs2, R2b, bnsum);
    // fused BN + MLP head
    k_final<<<(NN + 255) / 256, 256, 0, stream>>>(R2b, bnsum, gamma, beta, Wt3, l1b, l2W, l2b, out);
}

// Round 3
// 367.824 us; speedup vs baseline: 1.1657x; 1.0521x over previous
//
#include <hip/hip_runtime.h>
#include <math.h>

#define NN 50000
#define NE 500000
#define NREL 4
#define D 128
#define RSZ 512                 // dst-range size (one bin)
#define NRANGE 98               // ceil(NN/512)
#define NBK (NREL * NRANGE)     // 392 sort blocks
#define BCAP 6144               // per-(range,rel) csr capacity (mean 5120, +14 sigma)
#define NCH 128                 // edge chunks per relation
#define CH 3907                 // edges per chunk (128*3907 >= 500000)
#define FCAP 96                 // frag capacity per (chunk,bin): mean 40, +9 sigma
#define CAST_BLKS 6250          // NN*D/4/256
static constexpr float BN_EPS = 1e-5f;

typedef __attribute__((ext_vector_type(8))) _Float16 half8;
typedef __attribute__((ext_vector_type(4))) float f32x4;

__device__ __forceinline__ unsigned short f2h_bits(float f) {
    _Float16 h = (_Float16)f;  // v_cvt_f16_f32 (RTNE)
    return __builtin_bit_cast(unsigned short, h);
}
__device__ __forceinline__ float hi2f(unsigned p) {  // f16 in high 16 bits -> f32
    return (float)__builtin_bit_cast(_Float16, (unsigned short)(p >> 16));
}

// ---------------- fused prologue: cast x->f16, weight transpose+cast, bias sums, bnsum zero ----
__global__ __launch_bounds__(256) void k_pre(const float* __restrict__ x,
                                             const float* __restrict__ W1, const float* __restrict__ W2,
                                             const float* __restrict__ l1W, const float* __restrict__ b1,
                                             const float* __restrict__ b2,
                                             unsigned short* __restrict__ xb,
                                             unsigned short* __restrict__ Wt1,
                                             unsigned short* __restrict__ Wt2,
                                             unsigned short* __restrict__ Wt3,
                                             float* __restrict__ bs1, float* __restrict__ bs2,
                                             float* __restrict__ bnsum) {
    int blk = blockIdx.x, tid = threadIdx.x;
    if (blk < CAST_BLKS) {
        int i = blk * 256 + tid;
        float4 v = *(const float4*)(x + (size_t)i * 4);
        unsigned short u[4] = {f2h_bits(v.x), f2h_bits(v.y), f2h_bits(v.z), f2h_bits(v.w)};
        *(ushort4*)(xb + (size_t)i * 4) = *(ushort4*)u;
    } else if (blk < CAST_BLKS + 256) {
        int i = (blk - CAST_BLKS) * 256 + tid;  // [0, 65536)
        int kk = i & 511, n = i >> 9;           // coalesced stores along kk
        Wt1[n * 512 + kk] = f2h_bits(W1[kk * 128 + n]);
        Wt2[n * 512 + kk] = f2h_bits(W2[kk * 128 + n]);
    } else if (blk < CAST_BLKS + 320) {
        int i = (blk - CAST_BLKS - 256) * 256 + tid;  // [0, 16384)
        int kk = i & 127, n = i >> 7;
        Wt3[n * 128 + kk] = f2h_bits(l1W[kk * 128 + n]);
    } else {
        if (tid < 128) {
            bs1[tid] = b1[tid] + b1[128 + tid] + b1[256 + tid] + b1[384 + tid];
            bs2[tid] = b2[tid] + b2[128 + tid] + b2[256 + tid] + b2[384 + tid];
        }
        bnsum[tid] = 0.f;  // 256 floats
    }
}

// ---------------- pass A: bin edges into (chunk, range) fragment windows ----------------
// packed = src | dstlocal<<16 (src<50000 fits 16 bits, dstlocal 9 bits)
__global__ __launch_bounds__(256) void k_bin(const int* __restrict__ ei,
                                             int* __restrict__ frag,
                                             int* __restrict__ cntg) {
    int c = blockIdx.x, r = blockIdx.y;
    const int* srcp = ei + r * 2 * NE;
    const int* dstp = srcp + NE;
    __shared__ int bins[NRANGE * FCAP];  // 37.6 KB
    __shared__ int cnt[NRANGE];
    int tid = threadIdx.x;
    for (int i = tid; i < NRANGE; i += 256) cnt[i] = 0;
    __syncthreads();
    int e0 = c * CH, e1 = min(e0 + CH, NE);
    for (int e = e0 + tid; e < e1; e += 256) {
        int d = dstp[e];
        int s = srcp[e];
        int q = d >> 9;
        int pos = atomicAdd(&cnt[q], 1);
        if (pos < FCAP) bins[q * FCAP + pos] = s | ((d & 511) << 16);
    }
    __syncthreads();
    int w = tid >> 6, lane = tid & 63;
    for (int q = w; q < NRANGE; q += 4) {
        int k = min(cnt[q], FCAP);
        int gbase = ((r * NRANGE + q) * NCH + c) * FCAP;
        for (int i = lane; i < k; i += 64) frag[gbase + i] = bins[q * FCAP + i];
    }
    for (int q = tid; q < NRANGE; q += 256) cntg[(r * NRANGE + q) * NCH + c] = min(cnt[q], FCAP);
}

// ---------------- pass B: per (range, rel) counting-sort into CSR ----------------
__global__ __launch_bounds__(512) void k_sortb(const int* __restrict__ frag,
                                               const int* __restrict__ cntg,
                                               unsigned short* __restrict__ csr,
                                               int* __restrict__ rstart,
                                               int* __restrict__ rend,
                                               float* __restrict__ dinv) {
    int q = blockIdx.x, r = blockIdx.y;
    int blk = r * NRANGE + q;
    int n0 = q * RSZ;
    int nrows = min(RSZ, NN - n0);
    __shared__ int cnts[NCH], cbase[NCH];
    __shared__ int stage[BCAP];          // 24 KB
    __shared__ unsigned short csr_s[BCAP];
    __shared__ int hist[RSZ], off[RSZ], cnt2[RSZ];
    int tid = threadIdx.x;
    hist[tid] = 0;
    cnt2[tid] = 0;
    if (tid < NCH) cnts[tid] = cntg[blk * NCH + tid];
    __syncthreads();
    // exclusive scan of 128 chunk counts
    if (tid < NCH) cbase[tid] = cnts[tid];
    __syncthreads();
    for (int d = 1; d < NCH; d <<= 1) {
        int t = 0;
        if (tid < NCH && tid >= d) t = cbase[tid - d];
        __syncthreads();
        if (tid < NCH) cbase[tid] += t;
        __syncthreads();
    }
    if (tid < NCH) cbase[tid] -= cnts[tid];
    __syncthreads();
    int tot = cbase[NCH - 1] + cnts[NCH - 1];
    // parallel gather of all 128 fragment windows (4 threads per chunk)
    {
        int g = tid >> 2, l = tid & 3;
        int k = cnts[g], cb = cbase[g];
        int gbase = (blk * NCH + g) * FCAP;
        for (int i = l; i < k; i += 4)
            if (cb + i < BCAP) stage[cb + i] = frag[gbase + i];
    }
    __syncthreads();
    if (tot > BCAP) tot = BCAP;
    // histogram over dst-local
    for (int i = tid; i < tot; i += 512) atomicAdd(&hist[(stage[i] >> 16) & 511], 1);
    __syncthreads();
    int h = hist[tid];
    if (tid < nrows) dinv[r * NN + n0 + tid] = rsqrtf((float)(h + 1));  // +1 self loop
    // inclusive scan -> exclusive offsets
    off[tid] = h;
    __syncthreads();
    for (int d = 1; d < RSZ; d <<= 1) {
        int t = (tid >= d) ? off[tid - d] : 0;
        __syncthreads();
        off[tid] += t;
        __syncthreads();
    }
    int excl = off[tid] - h;
    __syncthreads();
    off[tid] = excl;
    int base = blk * BCAP;
    if (tid < nrows) {
        rstart[r * NN + n0 + tid] = base + excl;
        rend[r * NN + n0 + tid] = base + excl + h;
    }
    __syncthreads();
    // counting-sort into LDS
    for (int i = tid; i < tot; i += 512) {
        int v = stage[i];
        int dl = (v >> 16) & 511;
        int p = atomicAdd(&cnt2[dl], 1);
        csr_s[off[dl] + p] = (unsigned short)(v & 0xFFFF);
    }
    __syncthreads();
    // coalesced block-private write-out
    for (int i = tid; i < tot; i += 512) csr[base + i] = csr_s[i];
}

// ---------------- fill packed per-edge words: wpack[i] = src | f16(dinv[r][src])<<16 ----------
// One 4B load then feeds BOTH k_agg passes (replaces separate csr u16 + wcsr f32 loads).
__global__ __launch_bounds__(256) void k_wei(const unsigned short* __restrict__ csr,
                                             const float* __restrict__ dinv,
                                             unsigned* __restrict__ wpack) {
    int gi = blockIdx.x * 256 + threadIdx.x;
    int r = gi / (NRANGE * BCAP);
    int s = csr[gi];                       // garbage in gaps is harmless (masked in k_agg)
    float w = dinv[r * NN + min(s, NN - 1)];
    wpack[gi] = (unsigned)s | ((unsigned)f2h_bits(w) << 16);
}

// ---------------- aggregation: wave = node, quarter = relation ----------------
// 50K waves (4x fewer), each with 4 independent gather chains (one per relation) in one
// instruction stream -> 8 row-misses in flight per batch, double the miss-level parallelism.
// Quarter q (16 lanes, t = lane&15) owns relation q's full 128 cols (8 per lane): no
// cross-lane reduce, dense 1KB/wave coalesced store. Self-loop folded into acc init.
// Window: one packed 4B load per edge slot, distributed by ds_bpermute shuffles.
__global__ __launch_bounds__(256) void k_agg(const unsigned short* __restrict__ in,  // f16 [NN][128]
                                             const unsigned* __restrict__ wpack,
                                             const int* __restrict__ rstart,
                                             const int* __restrict__ rend,
                                             const float* __restrict__ dinv,         // [NREL][NN]
                                             unsigned short* __restrict__ Acat) {    // f16 [NN][512]
    int wave = threadIdx.x >> 6, lane = threadIdx.x & 63;
    int n = blockIdx.x * 4 + wave;
    if (n >= NN) return;
    int t = lane & 15;
    int base = lane & 48;  // q<<4
    int nb = (base >> 4) * NN + n;  // q*NN + n
    const half8* in8 = (const half8*)in;
    float wn = dinv[nb];
    int start = rstart[nb];
    int deg = rend[nb] - start;
    // wave-uniform max degree over the 4 quarters -> branchless uniform trip
    int dm = deg;
    dm = max(dm, __shfl_xor(dm, 16));
    dm = max(dm, __shfl_xor(dm, 32));
    // acc init = self-loop contribution (wn * x_n); final scale by wn at the end
    half8 us = in8[(size_t)n * 16 + t];
    float a[8];
#pragma unroll
    for (int j = 0; j < 8; j++) a[j] = wn * (float)us[j];

    for (int w0 = 0; w0 < dm; w0 += 16) {
        // cooperative window: lane holds edge (w0 + t) of ITS quarter's list
        int li = w0 + t;
        int gi = min(start + li, NBK * BCAP - 1);
        unsigned pv = wpack[gi];
        if (li >= deg) pv = 0u;  // src=0, w=+0.0 (row 0 load, L1-hot, adds zero)
        // batch A: edges 0..7 of this window
        unsigned p0 = __shfl(pv, base + 0), p1 = __shfl(pv, base + 1);
        unsigned p2 = __shfl(pv, base + 2), p3 = __shfl(pv, base + 3);
        unsigned p4 = __shfl(pv, base + 4), p5 = __shfl(pv, base + 5);
        unsigned p6 = __shfl(pv, base + 6), p7 = __shfl(pv, base + 7);
        {
            half8 r0 = in8[(p0 & 0xFFFFu) * 16 + t];
            half8 r1 = in8[(p1 & 0xFFFFu) * 16 + t];
            half8 r2 = in8[(p2 & 0xFFFFu) * 16 + t];
            half8 r3 = in8[(p3 & 0xFFFFu) * 16 + t];
            half8 r4 = in8[(p4 & 0xFFFFu) * 16 + t];
            half8 r5 = in8[(p5 & 0xFFFFu) * 16 + t];
            half8 r6 = in8[(p6 & 0xFFFFu) * 16 + t];
            half8 r7 = in8[(p7 & 0xFFFFu) * 16 + t];
            float w0f = hi2f(p0), w1f = hi2f(p1), w2f = hi2f(p2), w3f = hi2f(p3);
            float w4f = hi2f(p4), w5f = hi2f(p5), w6f = hi2f(p6), w7f = hi2f(p7);
#pragma unroll
            for (int j = 0; j < 8; j++) a[j] = fmaf((float)r0[j], w0f, a[j]);
#pragma unroll
            for (int j = 0; j < 8; j++) a[j] = fmaf((float)r1[j], w1f, a[j]);
#pragma unroll
            for (int j = 0; j < 8; j++) a[j] = fmaf((float)r2[j], w2f, a[j]);
#pragma unroll
            for (int j = 0; j < 8; j++) a[j] = fmaf((float)r3[j], w3f, a[j]);
#pragma unroll
            for (int j = 0; j < 8; j++) a[j] = fmaf((float)r4[j], w4f, a[j]);
#pragma unroll
            for (int j = 0; j < 8; j++) a[j] = fmaf((float)r5[j], w5f, a[j]);
#pragma unroll
            for (int j = 0; j < 8; j++) a[j] = fmaf((float)r6[j], w6f, a[j]);
#pragma unroll
            for (int j = 0; j < 8; j++) a[j] = fmaf((float)r7[j], w7f, a[j]);
        }
        if (w0 + 8 >= dm) continue;  // uniform branch: skip batch B if window <= 8 edges
        // batch B: edges 8..15
        p0 = __shfl(pv, base + 8);  p1 = __shfl(pv, base + 9);
        p2 = __shfl(pv, base + 10); p3 = __shfl(pv, base + 11);
        p4 = __shfl(pv, base + 12); p5 = __shfl(pv, base + 13);
        p6 = __shfl(pv, base + 14); p7 = __shfl(pv, base + 15);
        {
            half8 r0 = in8[(p0 & 0xFFFFu) * 16 + t];
            half8 r1 = in8[(p1 & 0xFFFFu) * 16 + t];
            half8 r2 = in8[(p2 & 0xFFFFu) * 16 + t];
            half8 r3 = in8[(p3 & 0xFFFFu) * 16 + t];
            half8 r4 = in8[(p4 & 0xFFFFu) * 16 + t];
            half8 r5 = in8[(p5 & 0xFFFFu) * 16 + t];
            half8 r6 = in8[(p6 & 0xFFFFu) * 16 + t];
            half8 r7 = in8[(p7 & 0xFFFFu) * 16 + t];
            float w0f = hi2f(p0), w1f = hi2f(p1), w2f = hi2f(p2), w3f = hi2f(p3);
            float w4f = hi2f(p4), w5f = hi2f(p5), w6f = hi2f(p6), w7f = hi2f(p7);
#pragma unroll
            for (int j = 0; j < 8; j++) a[j] = fmaf((float)r0[j], w0f, a[j]);
#pragma unroll
            for (int j = 0; j < 8; j++) a[j] = fmaf((float)r1[j], w1f, a[j]);
#pragma unroll
            for (int j = 0; j < 8; j++) a[j] = fmaf((float)r2[j], w2f, a[j]);
#pragma unroll
            for (int j = 0; j < 8; j++) a[j] = fmaf((float)r3[j], w3f, a[j]);
#pragma unroll
            for (int j = 0; j < 8; j++) a[j] = fmaf((float)r4[j], w4f, a[j]);
#pragma unroll
            for (int j = 0; j < 8; j++) a[j] = fmaf((float)r5[j], w5f, a[j]);
#pragma unroll
            for (int j = 0; j < 8; j++) a[j] = fmaf((float)r6[j], w6f, a[j]);
#pragma unroll
            for (int j = 0; j < 8; j++) a[j] = fmaf((float)r7[j], w7f, a[j]);
        }
    }
    // final dst scale + write: 64 lanes x 16B = 1KB contiguous per node
    _Float16 ob[8];
#pragma unroll
    for (int j = 0; j < 8; j++) ob[j] = (_Float16)(wn * a[j]);
    *(half8*)(Acat + (size_t)n * 512 + (base << 3) + t * 8) = *(half8*)ob;
}

// ---------------- MFMA GEMM: C[NN][128] = relu(A[NN][K] @ W[K][128] + bias) (f16 in/out) ----------------
template <int K, bool STATS>
__global__ __launch_bounds__(256) void k_mm(const unsigned short* __restrict__ A,
                                            const unsigned short* __restrict__ Bt,
                                            const float* __restrict__ bias,
                                            unsigned short* __restrict__ C,
                                            float* __restrict__ bnsum) {
    int tid = threadIdx.x;
    int w = tid >> 6, lane = tid & 63;
    int ln = lane & 15, quad = lane >> 4;
    int mwave = blockIdx.x * 256 + w * 64;

    f32x4 acc[4][8];
#pragma unroll
    for (int a = 0; a < 4; a++)
#pragma unroll
        for (int b = 0; b < 8; b++) acc[a][b] = (f32x4){0.f, 0.f, 0.f, 0.f};

    size_t arow[4];
#pragma unroll
    for (int mf = 0; mf < 4; mf++) {
        int m = mwave + mf * 16 + ln;
        arow[mf] = (size_t)min(m, NN - 1) * K;  // clamp; garbage rows guarded at store
    }
    size_t brow[8];
#pragma unroll
    for (int nf = 0; nf < 8; nf++) brow[nf] = (size_t)(nf * 16 + ln) * K;

    for (int k0 = 0; k0 < K; k0 += 32) {
        int kof = k0 + quad * 8;
        half8 af[4], bf[8];
#pragma unroll
        for (int mf = 0; mf < 4; mf++) af[mf] = *(const half8*)(A + arow[mf] + kof);
#pragma unroll
        for (int nf = 0; nf < 8; nf++) bf[nf] = *(const half8*)(Bt + brow[nf] + kof);
#pragma unroll
        for (int mf = 0; mf < 4; mf++)
#pragma unroll
            for (int nf = 0; nf < 8; nf++)
                acc[mf][nf] = __builtin_amdgcn_mfma_f32_16x16x32_f16(af[mf], bf[nf], acc[mf][nf], 0, 0, 0);
    }

    float bs[8];
#pragma unroll
    for (int nf = 0; nf < 8; nf++) bs[nf] = bias[nf * 16 + ln];
    float sn[8], qn[8];
#pragma unroll
    for (int nf = 0; nf < 8; nf++) { sn[nf] = 0.f; qn[nf] = 0.f; }

#pragma unroll
    for (int mf = 0; mf < 4; mf++)
#pragma unroll
        for (int nf = 0; nf < 8; nf++)
#pragma unroll
            for (int rg = 0; rg < 4; rg++) {
                int m = mwave + mf * 16 + quad * 4 + rg;
                if (m < NN) {
                    float v = fmaxf(acc[mf][nf][rg] + bs[nf], 0.f);
                    if (STATS) { sn[nf] += v; qn[nf] += v * v; }
                    C[(size_t)m * 128 + nf * 16 + ln] = f2h_bits(v);
                }
            }

    if (STATS) {
#pragma unroll
        for (int nf = 0; nf < 8; nf++) {
            float s = sn[nf], q = qn[nf];
            s += __shfl_xor(s, 16); s += __shfl_xor(s, 32);
            q += __shfl_xor(q, 16); q += __shfl_xor(q, 32);
            if (quad == 0) {
                unsafeAtomicAdd(&bnsum[nf * 16 + ln], s);
                unsafeAtomicAdd(&bnsum[128 + nf * 16 + ln], q);
            }
        }
    }
}

// ---------------- final: BN affine from bnsum + relu(BN(R2)@l1W+l1b)@l2W+l2b ----------------
__global__ __launch_bounds__(256) void k_final(const unsigned short* __restrict__ R2,
                                               const float* __restrict__ bnsum,
                                               const float* __restrict__ gamma,
                                               const float* __restrict__ beta,
                                               const unsigned short* __restrict__ Wt3,
                                               const float* __restrict__ l1b,
                                               const float* __restrict__ l2W,
                                               const float* __restrict__ l2b,
                                               float* __restrict__ out) {
    __shared__ float bnp_s[256];
    int tid = threadIdx.x;
    if (tid < 128) {
        float mean = bnsum[tid] / (float)NN;
        float var = bnsum[128 + tid] / (float)NN - mean * mean;
        float sc = gamma[tid] * rsqrtf(var + BN_EPS);
        bnp_s[tid] = sc;
        bnp_s[128 + tid] = beta[tid] - mean * sc;
    }
    __syncthreads();
    int w = tid >> 6, lane = tid & 63;
    int ln = lane & 15, quad = lane >> 4;
    int mwave = blockIdx.x * 256 + w * 64;

    f32x4 acc[4][8];
#pragma unroll
    for (int a = 0; a < 4; a++)
#pragma unroll
        for (int b = 0; b < 8; b++) acc[a][b] = (f32x4){0.f, 0.f, 0.f, 0.f};

    size_t arow[4];
#pragma unroll
    for (int mf = 0; mf < 4; mf++) {
        int m = mwave + mf * 16 + ln;
        arow[mf] = (size_t)min(m, NN - 1) * 128;
    }
    size_t brow[8];
#pragma unroll
    for (int nf = 0; nf < 8; nf++) brow[nf] = (size_t)(nf * 16 + ln) * 128;

    for (int k0 = 0; k0 < 128; k0 += 32) {
        int kof = k0 + quad * 8;
        float scv[8], shv[8];
#pragma unroll
        for (int j = 0; j < 8; j++) {
            scv[j] = bnp_s[kof + j];
            shv[j] = bnp_s[128 + kof + j];
        }
        half8 af[4], bf[8];
#pragma unroll
        for (int mf = 0; mf < 4; mf++) {
            half8 rv = *(const half8*)(R2 + arow[mf] + kof);
            _Float16 ab[8];
#pragma unroll
            for (int j = 0; j < 8; j++)
                ab[j] = (_Float16)(fmaf((float)rv[j], scv[j], shv[j]));
            af[mf] = *(half8*)ab;
        }
#pragma unroll
        for (int nf = 0; nf < 8; nf++) bf[nf] = *(const half8*)(Wt3 + brow[nf] + kof);
#pragma unroll
        for (int mf = 0; mf < 4; mf++)
#pragma unroll
            for (int nf = 0; nf < 8; nf++)
                acc[mf][nf] = __builtin_amdgcn_mfma_f32_16x16x32_f16(af[mf], bf[nf], acc[mf][nf], 0, 0, 0);
    }

    float b1v[8], w0[8], w1[8];
#pragma unroll
    for (int nf = 0; nf < 8; nf++) {
        int n = nf * 16 + ln;
        b1v[nf] = l1b[n];
        w0[nf] = l2W[n * 2];
        w1[nf] = l2W[n * 2 + 1];
    }
    float ob0 = l2b[0], ob1 = l2b[1];
#pragma unroll
    for (int mf = 0; mf < 4; mf++)
#pragma unroll
        for (int rg = 0; rg < 4; rg++) {
            float p0 = 0.f, p1 = 0.f;
#pragma unroll
            for (int nf = 0; nf < 8; nf++) {
                float y = fmaxf(acc[mf][nf][rg] + b1v[nf], 0.f);
                p0 += y * w0[nf];
                p1 += y * w1[nf];
            }
            p0 += __shfl_xor(p0, 1); p0 += __shfl_xor(p0, 2);
            p0 += __shfl_xor(p0, 4); p0 += __shfl_xor(p0, 8);
            p1 += __shfl_xor(p1, 1); p1 += __shfl_xor(p1, 2);
            p1 += __shfl_xor(p1, 4); p1 += __shfl_xor(p1, 8);
            int m = mwave + mf * 16 + quad * 4 + rg;
            if (ln == 0 && m < NN) {
                out[(size_t)m * 2 + 0] = p0 + ob0;
                out[(size_t)m * 2 + 1] = p1 + ob1;
            }
        }
}

extern "C" void kernel_launch(void* const* d_in, const int* in_sizes, int n_in,
                              void* d_out, int out_size, void* d_ws, size_t ws_size,
                              hipStream_t stream) {
    const float* x = (const float*)d_in[0];
    const int* ei = (const int*)d_in[1];
    const float* W1 = (const float*)d_in[2];
    const float* b1 = (const float*)d_in[3];
    const float* W2 = (const float*)d_in[4];
    const float* b2 = (const float*)d_in[5];
    const float* gamma = (const float*)d_in[6];
    const float* beta = (const float*)d_in[7];
    const float* l1W = (const float*)d_in[8];
    const float* l1b = (const float*)d_in[9];
    const float* l2W = (const float*)d_in[10];
    const float* l2b = (const float*)d_in[11];
    float* out = (float*)d_out;

    char* ws = (char*)d_ws;
    size_t off = 0;
    auto alloc = [&](size_t bytes) {
        void* p = ws + off;
        off += (bytes + 255) & ~(size_t)255;
        return p;
    };
    float* dinv = (float*)alloc((size_t)NREL * NN * sizeof(float));
    int* rstart = (int*)alloc((size_t)NREL * NN * sizeof(int));
    int* rend = (int*)alloc((size_t)NREL * NN * sizeof(int));
    unsigned short* csr = (unsigned short*)alloc((size_t)NBK * BCAP * 2);            // 4.8 MB
    unsigned short* xb = (unsigned short*)alloc((size_t)NN * D * 2);                 // 12.8 MB
    unsigned short* Acat = (unsigned short*)alloc((size_t)NN * 512 * 2);             // 51.2 MB
    unsigned short* h1b = (unsigned short*)alloc((size_t)NN * D * 2);                // 12.8 MB
    unsigned short* R2b = (unsigned short*)alloc((size_t)NN * D * 2);                // 12.8 MB
    unsigned short* Wt1 = (unsigned short*)alloc(128 * 512 * 2);
    unsigned short* Wt2 = (unsigned short*)alloc(128 * 512 * 2);
    unsigned short* Wt3 = (unsigned short*)alloc(128 * 128 * 2);
    float* bs1 = (float*)alloc(128 * sizeof(float));
    float* bs2 = (float*)alloc(128 * sizeof(float));
    float* bnsum = (float*)alloc(256 * sizeof(float));

    // frag/cntg alias Acat's storage (dead until k_agg writes it, after k_sortb completes)
    int* frag = (int*)Acat;                                       // 19.3 MB
    int* cntg = frag + (size_t)NREL * NRANGE * NCH * FCAP;        // 0.2 MB
    // wpack (9.63 MB u32) aliases R2b: R2b is first written by k_mm<512,true>, which is
    // stream-ordered AFTER the last wpack read (k_agg #2). No workspace growth.
    unsigned* wpack = (unsigned*)R2b;

    k_pre<<<CAST_BLKS + 321, 256, 0, stream>>>(x, W1, W2, l1W, b1, b2, xb, Wt1, Wt2, Wt3,
                                               bs1, bs2, bnsum);
    dim3 bgrid(NCH, NREL);
    k_bin<<<bgrid, 256, 0, stream>>>(ei, frag, cntg);
    dim3 sgrid(NRANGE, NREL);
    k_sortb<<<sgrid, 512, 0, stream>>>(frag, cntg, csr, rstart, rend, dinv);
    k_wei<<<(NBK * BCAP) / 256, 256, 0, stream>>>(csr, dinv, wpack);

    int agrid = (NN + 3) / 4;  // wave = node (all 4 relations)
    // layer 1: aggregate x per relation -> Acat (concat), then one K=512 GEMM
    k_agg<<<agrid, 256, 0, stream>>>(xb, wpack, rstart, rend, dinv, Acat);
    k_mm<512, false><<<(NN + 255) / 256, 256, 0, stream>>>(Acat, Wt1, bs1, h1b, nullptr);
    // layer 2
    k_agg<<<agrid, 256, 0, stream>>>(h1b, wpack, rstart, rend, dinv, Acat);
    k_mm<512, true><<<(NN + 255) / 256, 256, 0, stream>>>(Acat, Wt2, bs2, R2b, bnsum);
    // fused BN + MLP head
    k_final<<<(NN + 255) / 256, 256, 0, stream>>>(R2b, bnsum, gamma, beta, Wt3, l1b, l2W, l2b, out);
}

// Round 4
// 358.923 us; speedup vs baseline: 1.1946x; 1.0248x over previous
//
#include <hip/hip_runtime.h>
#include <math.h>

#define NN 50000
#define NE 500000
#define NREL 4
#define D 128
#define RSZ 512                 // dst-range size (one bin)
#define NRANGE 98               // ceil(NN/512)
#define NBK (NREL * NRANGE)     // 392 sort blocks
#define BCAP 6144               // per-(range,rel) csr capacity (mean 5120, +14 sigma)
#define NCH 128                 // edge chunks per relation
#define CH 3907                 // edges per chunk (128*3907 >= 500000)
#define FCAP 96                 // frag capacity per (chunk,bin): mean 40, +9 sigma
#define CAST_BLKS 6250          // NN*D/4/256
#define TN 32                   // nodes per fused tile
#define NPW 8                   // nodes per wave (TN / 4 waves)
#define NTILE ((NN + TN - 1) / TN)
static constexpr float BN_EPS = 1e-5f;

typedef __attribute__((ext_vector_type(8))) _Float16 half8;
typedef __attribute__((ext_vector_type(4))) float f32x4;

__device__ __forceinline__ unsigned short f2h_bits(float f) {
    _Float16 h = (_Float16)f;  // v_cvt_f16_f32 (RTNE)
    return __builtin_bit_cast(unsigned short, h);
}
__device__ __forceinline__ float hi2f(unsigned p) {  // f16 in high 16 bits -> f32
    return (float)__builtin_bit_cast(_Float16, (unsigned short)(p >> 16));
}

// ---------------- fused prologue: cast x->f16, weight transpose+cast, bias sums, bnsum zero ----
__global__ __launch_bounds__(256) void k_pre(const float* __restrict__ x,
                                             const float* __restrict__ W1, const float* __restrict__ W2,
                                             const float* __restrict__ l1W, const float* __restrict__ b1,
                                             const float* __restrict__ b2,
                                             unsigned short* __restrict__ xb,
                                             unsigned short* __restrict__ Wt1,
                                             unsigned short* __restrict__ Wt2,
                                             unsigned short* __restrict__ Wt3,
                                             float* __restrict__ bs1, float* __restrict__ bs2,
                                             float* __restrict__ bnsum) {
    int blk = blockIdx.x, tid = threadIdx.x;
    if (blk < CAST_BLKS) {
        int i = blk * 256 + tid;
        float4 v = *(const float4*)(x + (size_t)i * 4);
        unsigned short u[4] = {f2h_bits(v.x), f2h_bits(v.y), f2h_bits(v.z), f2h_bits(v.w)};
        *(ushort4*)(xb + (size_t)i * 4) = *(ushort4*)u;
    } else if (blk < CAST_BLKS + 256) {
        int i = (blk - CAST_BLKS) * 256 + tid;  // [0, 65536)
        int kk = i & 511, n = i >> 9;           // coalesced stores along kk
        Wt1[n * 512 + kk] = f2h_bits(W1[kk * 128 + n]);
        Wt2[n * 512 + kk] = f2h_bits(W2[kk * 128 + n]);
    } else if (blk < CAST_BLKS + 320) {
        int i = (blk - CAST_BLKS - 256) * 256 + tid;  // [0, 16384)
        int kk = i & 127, n = i >> 7;
        Wt3[n * 128 + kk] = f2h_bits(l1W[kk * 128 + n]);
    } else {
        if (tid < 128) {
            bs1[tid] = b1[tid] + b1[128 + tid] + b1[256 + tid] + b1[384 + tid];
            bs2[tid] = b2[tid] + b2[128 + tid] + b2[256 + tid] + b2[384 + tid];
        }
        bnsum[tid] = 0.f;  // 256 floats
    }
}

// ---------------- pass A: bin edges into (chunk, range) fragment windows ----------------
// packed = src | dstlocal<<16 (src<50000 fits 16 bits, dstlocal 9 bits)
__global__ __launch_bounds__(256) void k_bin(const int* __restrict__ ei,
                                             int* __restrict__ frag,
                                             int* __restrict__ cntg) {
    int c = blockIdx.x, r = blockIdx.y;
    const int* srcp = ei + r * 2 * NE;
    const int* dstp = srcp + NE;
    __shared__ int bins[NRANGE * FCAP];  // 37.6 KB
    __shared__ int cnt[NRANGE];
    int tid = threadIdx.x;
    for (int i = tid; i < NRANGE; i += 256) cnt[i] = 0;
    __syncthreads();
    int e0 = c * CH, e1 = min(e0 + CH, NE);
    for (int e = e0 + tid; e < e1; e += 256) {
        int d = dstp[e];
        int s = srcp[e];
        int q = d >> 9;
        int pos = atomicAdd(&cnt[q], 1);
        if (pos < FCAP) bins[q * FCAP + pos] = s | ((d & 511) << 16);
    }
    __syncthreads();
    int w = tid >> 6, lane = tid & 63;
    for (int q = w; q < NRANGE; q += 4) {
        int k = min(cnt[q], FCAP);
        int gbase = ((r * NRANGE + q) * NCH + c) * FCAP;
        for (int i = lane; i < k; i += 64) frag[gbase + i] = bins[q * FCAP + i];
    }
    for (int q = tid; q < NRANGE; q += 256) cntg[(r * NRANGE + q) * NCH + c] = min(cnt[q], FCAP);
}

// ---------------- pass B: per (range, rel) counting-sort into CSR ----------------
__global__ __launch_bounds__(512) void k_sortb(const int* __restrict__ frag,
                                               const int* __restrict__ cntg,
                                               unsigned short* __restrict__ csr,
                                               int* __restrict__ rstart,
                                               int* __restrict__ rend,
                                               float* __restrict__ dinv) {
    int q = blockIdx.x, r = blockIdx.y;
    int blk = r * NRANGE + q;
    int n0 = q * RSZ;
    int nrows = min(RSZ, NN - n0);
    __shared__ int cnts[NCH], cbase[NCH];
    __shared__ int stage[BCAP];          // 24 KB
    __shared__ unsigned short csr_s[BCAP];
    __shared__ int hist[RSZ], off[RSZ], cnt2[RSZ];
    int tid = threadIdx.x;
    hist[tid] = 0;
    cnt2[tid] = 0;
    if (tid < NCH) cnts[tid] = cntg[blk * NCH + tid];
    __syncthreads();
    // exclusive scan of 128 chunk counts
    if (tid < NCH) cbase[tid] = cnts[tid];
    __syncthreads();
    for (int d = 1; d < NCH; d <<= 1) {
        int t = 0;
        if (tid < NCH && tid >= d) t = cbase[tid - d];
        __syncthreads();
        if (tid < NCH) cbase[tid] += t;
        __syncthreads();
    }
    if (tid < NCH) cbase[tid] -= cnts[tid];
    __syncthreads();
    int tot = cbase[NCH - 1] + cnts[NCH - 1];
    // parallel gather of all 128 fragment windows (4 threads per chunk)
    {
        int g = tid >> 2, l = tid & 3;
        int k = cnts[g], cb = cbase[g];
        int gbase = (blk * NCH + g) * FCAP;
        for (int i = l; i < k; i += 4)
            if (cb + i < BCAP) stage[cb + i] = frag[gbase + i];
    }
    __syncthreads();
    if (tot > BCAP) tot = BCAP;
    // histogram over dst-local
    for (int i = tid; i < tot; i += 512) atomicAdd(&hist[(stage[i] >> 16) & 511], 1);
    __syncthreads();
    int h = hist[tid];
    if (tid < nrows) dinv[r * NN + n0 + tid] = rsqrtf((float)(h + 1));  // +1 self loop
    // inclusive scan -> exclusive offsets
    off[tid] = h;
    __syncthreads();
    for (int d = 1; d < RSZ; d <<= 1) {
        int t = (tid >= d) ? off[tid - d] : 0;
        __syncthreads();
        off[tid] += t;
        __syncthreads();
    }
    int excl = off[tid] - h;
    __syncthreads();
    off[tid] = excl;
    int base = blk * BCAP;
    if (tid < nrows) {
        rstart[r * NN + n0 + tid] = base + excl;
        rend[r * NN + n0 + tid] = base + excl + h;
    }
    __syncthreads();
    // counting-sort into LDS
    for (int i = tid; i < tot; i += 512) {
        int v = stage[i];
        int dl = (v >> 16) & 511;
        int p = atomicAdd(&cnt2[dl], 1);
        csr_s[off[dl] + p] = (unsigned short)(v & 0xFFFF);
    }
    __syncthreads();
    // coalesced block-private write-out
    for (int i = tid; i < tot; i += 512) csr[base + i] = csr_s[i];
}

// ---------------- fill packed per-edge words: wpack[i] = src | f16(dinv[r][src])<<16 ----------
__global__ __launch_bounds__(256) void k_wei(const unsigned short* __restrict__ csr,
                                             const float* __restrict__ dinv,
                                             unsigned* __restrict__ wpack) {
    int gi = blockIdx.x * 256 + threadIdx.x;
    int r = gi / (NRANGE * BCAP);
    int s = csr[gi];                       // garbage in gaps is harmless (masked in k_fused)
    float w = dinv[r * NN + min(s, NN - 1)];
    wpack[gi] = (unsigned)s | ((unsigned)f2h_bits(w) << 16);
}

// ---------------- FUSED aggregate + GEMM per 32-node tile ----------------
// Phase 1 (gather): wave = node (8 sequential nodes/wave), quarter = relation. Aggregated
// 512-col concat row written to XOR-swizzled LDS (byte ^= (row&7)<<4 kills the 1024B-stride
// bank conflict on phase-2 ds_read_b128). Removes the Acat 51.2MB write + 51.2MB re-read.
// Next-node descriptors + self-row prefetched one node ahead to pipeline the serial chain.
// Phase 2 (GEMM): C[tile] = relu(A_lds[32][512] @ Wt[512->128] + bias); waves col-split so
// Wt is read once per block (L2-hot). Optional BN stats accumulation.
template <bool STATS>
__global__ __launch_bounds__(256) void k_fused(const unsigned short* __restrict__ in,   // f16 [NN][128]
                                               const unsigned* __restrict__ wpack,
                                               const int* __restrict__ rstart,
                                               const int* __restrict__ rend,
                                               const float* __restrict__ dinv,          // [NREL][NN]
                                               const unsigned short* __restrict__ Bt,   // f16 [128][512]
                                               const float* __restrict__ bias,
                                               unsigned short* __restrict__ C,          // f16 [NN][128]
                                               float* __restrict__ bnsum) {
    __shared__ unsigned short A_s[TN * 512];  // 32 KB, swizzled
    int tid = threadIdx.x;
    int wave = tid >> 6, lane = tid & 63;
    int t = lane & 15;
    int base = lane & 48;   // quarter<<4
    int q = base >> 4;      // relation
    int tile = blockIdx.x;
    const half8* in8 = (const half8*)in;
    int nbq = q * NN;

    // ---- phase 1: gather 8 nodes ----
    int row0 = wave * NPW;
    {
        int n0 = tile * TN + row0;
        int nc0 = min(n0, NN - 1);
        int sP = rstart[nbq + nc0];
        int eP = rend[nbq + nc0];
        float wP = dinv[nbq + nc0];
        half8 uP = in8[(size_t)nc0 * 16 + t];
        for (int i = 0; i < NPW; ++i) {
            int row = row0 + i;
            int n = tile * TN + row;
            bool valid = (n < NN);
            int start = sP;
            int deg = valid ? (eP - sP) : 0;
            float wn = valid ? wP : 0.f;
            half8 us = uP;
            if (i + 1 < NPW) {  // prefetch next node (issues before the dependent chain below)
                int nn = min(n + 1, NN - 1);
                sP = rstart[nbq + nn];
                eP = rend[nbq + nn];
                wP = dinv[nbq + nn];
                uP = in8[(size_t)nn * 16 + t];
            }
            int dm = deg;
            dm = max(dm, __shfl_xor(dm, 16));
            dm = max(dm, __shfl_xor(dm, 32));
            float a[8];
#pragma unroll
            for (int j = 0; j < 8; j++) a[j] = wn * (float)us[j];

            for (int w0 = 0; w0 < dm; w0 += 16) {
                int li = w0 + t;
                int gi = min(start + li, NBK * BCAP - 1);
                unsigned pv = wpack[gi];
                if (li >= deg) pv = 0u;  // src=0, w=+0.0 (row 0 L1-hot, adds zero)
                unsigned p0 = __shfl(pv, base + 0), p1 = __shfl(pv, base + 1);
                unsigned p2 = __shfl(pv, base + 2), p3 = __shfl(pv, base + 3);
                unsigned p4 = __shfl(pv, base + 4), p5 = __shfl(pv, base + 5);
                unsigned p6 = __shfl(pv, base + 6), p7 = __shfl(pv, base + 7);
                {
                    half8 r0 = in8[(p0 & 0xFFFFu) * 16 + t];
                    half8 r1 = in8[(p1 & 0xFFFFu) * 16 + t];
                    half8 r2 = in8[(p2 & 0xFFFFu) * 16 + t];
                    half8 r3 = in8[(p3 & 0xFFFFu) * 16 + t];
                    half8 r4 = in8[(p4 & 0xFFFFu) * 16 + t];
                    half8 r5 = in8[(p5 & 0xFFFFu) * 16 + t];
                    half8 r6 = in8[(p6 & 0xFFFFu) * 16 + t];
                    half8 r7 = in8[(p7 & 0xFFFFu) * 16 + t];
                    float w0f = hi2f(p0), w1f = hi2f(p1), w2f = hi2f(p2), w3f = hi2f(p3);
                    float w4f = hi2f(p4), w5f = hi2f(p5), w6f = hi2f(p6), w7f = hi2f(p7);
#pragma unroll
                    for (int j = 0; j < 8; j++) a[j] = fmaf((float)r0[j], w0f, a[j]);
#pragma unroll
                    for (int j = 0; j < 8; j++) a[j] = fmaf((float)r1[j], w1f, a[j]);
#pragma unroll
                    for (int j = 0; j < 8; j++) a[j] = fmaf((float)r2[j], w2f, a[j]);
#pragma unroll
                    for (int j = 0; j < 8; j++) a[j] = fmaf((float)r3[j], w3f, a[j]);
#pragma unroll
                    for (int j = 0; j < 8; j++) a[j] = fmaf((float)r4[j], w4f, a[j]);
#pragma unroll
                    for (int j = 0; j < 8; j++) a[j] = fmaf((float)r5[j], w5f, a[j]);
#pragma unroll
                    for (int j = 0; j < 8; j++) a[j] = fmaf((float)r6[j], w6f, a[j]);
#pragma unroll
                    for (int j = 0; j < 8; j++) a[j] = fmaf((float)r7[j], w7f, a[j]);
                }
                if (w0 + 8 >= dm) continue;
                p0 = __shfl(pv, base + 8);  p1 = __shfl(pv, base + 9);
                p2 = __shfl(pv, base + 10); p3 = __shfl(pv, base + 11);
                p4 = __shfl(pv, base + 12); p5 = __shfl(pv, base + 13);
                p6 = __shfl(pv, base + 14); p7 = __shfl(pv, base + 15);
                {
                    half8 r0 = in8[(p0 & 0xFFFFu) * 16 + t];
                    half8 r1 = in8[(p1 & 0xFFFFu) * 16 + t];
                    half8 r2 = in8[(p2 & 0xFFFFu) * 16 + t];
                    half8 r3 = in8[(p3 & 0xFFFFu) * 16 + t];
                    half8 r4 = in8[(p4 & 0xFFFFu) * 16 + t];
                    half8 r5 = in8[(p5 & 0xFFFFu) * 16 + t];
                    half8 r6 = in8[(p6 & 0xFFFFu) * 16 + t];
                    half8 r7 = in8[(p7 & 0xFFFFu) * 16 + t];
                    float w0f = hi2f(p0), w1f = hi2f(p1), w2f = hi2f(p2), w3f = hi2f(p3);
                    float w4f = hi2f(p4), w5f = hi2f(p5), w6f = hi2f(p6), w7f = hi2f(p7);
#pragma unroll
                    for (int j = 0; j < 8; j++) a[j] = fmaf((float)r0[j], w0f, a[j]);
#pragma unroll
                    for (int j = 0; j < 8; j++) a[j] = fmaf((float)r1[j], w1f, a[j]);
#pragma unroll
                    for (int j = 0; j < 8; j++) a[j] = fmaf((float)r2[j], w2f, a[j]);
#pragma unroll
                    for (int j = 0; j < 8; j++) a[j] = fmaf((float)r3[j], w3f, a[j]);
#pragma unroll
                    for (int j = 0; j < 8; j++) a[j] = fmaf((float)r4[j], w4f, a[j]);
#pragma unroll
                    for (int j = 0; j < 8; j++) a[j] = fmaf((float)r5[j], w5f, a[j]);
#pragma unroll
                    for (int j = 0; j < 8; j++) a[j] = fmaf((float)r6[j], w6f, a[j]);
#pragma unroll
                    for (int j = 0; j < 8; j++) a[j] = fmaf((float)r7[j], w7f, a[j]);
                }
            }
            // write swizzled LDS row (64 lanes x 16B = full 1KB row, bijective chunk permute)
            _Float16 ob[8];
#pragma unroll
            for (int j = 0; j < 8; j++) ob[j] = (_Float16)(wn * a[j]);
            int offb = row * 1024 + ((lane * 16) ^ ((row & 7) << 4));
            *(half8*)((char*)A_s + offb) = *(half8*)ob;
        }
    }
    __syncthreads();

    // ---- phase 2: GEMM from LDS ----
    int ln = lane & 15, quad = lane >> 4;
    f32x4 acc[2][2];
#pragma unroll
    for (int a = 0; a < 2; a++)
#pragma unroll
        for (int b = 0; b < 2; b++) acc[a][b] = (f32x4){0.f, 0.f, 0.f, 0.f};
    size_t brow[2];
#pragma unroll
    for (int nf = 0; nf < 2; nf++) brow[nf] = (size_t)(wave * 32 + nf * 16 + ln) * 512;

    for (int k0 = 0; k0 < 512; k0 += 32) {
        int kofb = k0 * 2 + quad * 16;  // byte col within row
        half8 af[2], bf[2];
#pragma unroll
        for (int mf = 0; mf < 2; mf++) {
            int rr = mf * 16 + ln;
            int offb = rr * 1024 + (kofb ^ ((rr & 7) << 4));
            af[mf] = *(const half8*)((const char*)A_s + offb);
        }
#pragma unroll
        for (int nf = 0; nf < 2; nf++) bf[nf] = *(const half8*)(Bt + brow[nf] + (kofb >> 1));
#pragma unroll
        for (int mf = 0; mf < 2; mf++)
#pragma unroll
            for (int nf = 0; nf < 2; nf++)
                acc[mf][nf] = __builtin_amdgcn_mfma_f32_16x16x32_f16(af[mf], bf[nf], acc[mf][nf], 0, 0, 0);
    }

    float bs[2];
#pragma unroll
    for (int nf = 0; nf < 2; nf++) bs[nf] = bias[wave * 32 + nf * 16 + ln];
    float sn[2] = {0.f, 0.f}, qn[2] = {0.f, 0.f};
#pragma unroll
    for (int mf = 0; mf < 2; mf++)
#pragma unroll
        for (int nf = 0; nf < 2; nf++)
#pragma unroll
            for (int rg = 0; rg < 4; rg++) {
                int m = tile * TN + mf * 16 + quad * 4 + rg;
                if (m < NN) {
                    float v = fmaxf(acc[mf][nf][rg] + bs[nf], 0.f);
                    if (STATS) { sn[nf] += v; qn[nf] += v * v; }
                    C[(size_t)m * 128 + wave * 32 + nf * 16 + ln] = f2h_bits(v);
                }
            }
    if (STATS) {
#pragma unroll
        for (int nf = 0; nf < 2; nf++) {
            float s = sn[nf], qq = qn[nf];
            s += __shfl_xor(s, 16); s += __shfl_xor(s, 32);
            qq += __shfl_xor(qq, 16); qq += __shfl_xor(qq, 32);
            if (quad == 0) {
                int col = wave * 32 + nf * 16 + ln;
                unsafeAtomicAdd(&bnsum[col], s);
                unsafeAtomicAdd(&bnsum[128 + col], qq);
            }
        }
    }
}

// ---------------- final: BN affine from bnsum + relu(BN(R2)@l1W+l1b)@l2W+l2b ----------------
__global__ __launch_bounds__(256) void k_final(const unsigned short* __restrict__ R2,
                                               const float* __restrict__ bnsum,
                                               const float* __restrict__ gamma,
                                               const float* __restrict__ beta,
                                               const unsigned short* __restrict__ Wt3,
                                               const float* __restrict__ l1b,
                                               const float* __restrict__ l2W,
                                               const float* __restrict__ l2b,
                                               float* __restrict__ out) {
    __shared__ float bnp_s[256];
    int tid = threadIdx.x;
    if (tid < 128) {
        float mean = bnsum[tid] / (float)NN;
        float var = bnsum[128 + tid] / (float)NN - mean * mean;
        float sc = gamma[tid] * rsqrtf(var + BN_EPS);
        bnp_s[tid] = sc;
        bnp_s[128 + tid] = beta[tid] - mean * sc;
    }
    __syncthreads();
    int w = tid >> 6, lane = tid & 63;
    int ln = lane & 15, quad = lane >> 4;
    int mwave = blockIdx.x * 256 + w * 64;

    f32x4 acc[4][8];
#pragma unroll
    for (int a = 0; a < 4; a++)
#pragma unroll
        for (int b = 0; b < 8; b++) acc[a][b] = (f32x4){0.f, 0.f, 0.f, 0.f};

    size_t arow[4];
#pragma unroll
    for (int mf = 0; mf < 4; mf++) {
        int m = mwave + mf * 16 + ln;
        arow[mf] = (size_t)min(m, NN - 1) * 128;
    }
    size_t brow[8];
#pragma unroll
    for (int nf = 0; nf < 8; nf++) brow[nf] = (size_t)(nf * 16 + ln) * 128;

    for (int k0 = 0; k0 < 128; k0 += 32) {
        int kof = k0 + quad * 8;
        float scv[8], shv[8];
#pragma unroll
        for (int j = 0; j < 8; j++) {
            scv[j] = bnp_s[kof + j];
            shv[j] = bnp_s[128 + kof + j];
        }
        half8 af[4], bf[8];
#pragma unroll
        for (int mf = 0; mf < 4; mf++) {
            half8 rv = *(const half8*)(R2 + arow[mf] + kof);
            _Float16 ab[8];
#pragma unroll
            for (int j = 0; j < 8; j++)
                ab[j] = (_Float16)(fmaf((float)rv[j], scv[j], shv[j]));
            af[mf] = *(half8*)ab;
        }
#pragma unroll
        for (int nf = 0; nf < 8; nf++) bf[nf] = *(const half8*)(Wt3 + brow[nf] + kof);
#pragma unroll
        for (int mf = 0; mf < 4; mf++)
#pragma unroll
            for (int nf = 0; nf < 8; nf++)
                acc[mf][nf] = __builtin_amdgcn_mfma_f32_16x16x32_f16(af[mf], bf[nf], acc[mf][nf], 0, 0, 0);
    }

    float b1v[8], w0[8], w1[8];
#pragma unroll
    for (int nf = 0; nf < 8; nf++) {
        int n = nf * 16 + ln;
        b1v[nf] = l1b[n];
        w0[nf] = l2W[n * 2];
        w1[nf] = l2W[n * 2 + 1];
    }
    float ob0 = l2b[0], ob1 = l2b[1];
#pragma unroll
    for (int mf = 0; mf < 4; mf++)
#pragma unroll
        for (int rg = 0; rg < 4; rg++) {
            float p0 = 0.f, p1 = 0.f;
#pragma unroll
            for (int nf = 0; nf < 8; nf++) {
                float y = fmaxf(acc[mf][nf][rg] + b1v[nf], 0.f);
                p0 += y * w0[nf];
                p1 += y * w1[nf];
            }
            p0 += __shfl_xor(p0, 1); p0 += __shfl_xor(p0, 2);
            p0 += __shfl_xor(p0, 4); p0 += __shfl_xor(p0, 8);
            p1 += __shfl_xor(p1, 1); p1 += __shfl_xor(p1, 2);
            p1 += __shfl_xor(p1, 4); p1 += __shfl_xor(p1, 8);
            int m = mwave + mf * 16 + quad * 4 + rg;
            if (ln == 0 && m < NN) {
                out[(size_t)m * 2 + 0] = p0 + ob0;
                out[(size_t)m * 2 + 1] = p1 + ob1;
            }
        }
}

extern "C" void kernel_launch(void* const* d_in, const int* in_sizes, int n_in,
                              void* d_out, int out_size, void* d_ws, size_t ws_size,
                              hipStream_t stream) {
    const float* x = (const float*)d_in[0];
    const int* ei = (const int*)d_in[1];
    const float* W1 = (const float*)d_in[2];
    const float* b1 = (const float*)d_in[3];
    const float* W2 = (const float*)d_in[4];
    const float* b2 = (const float*)d_in[5];
    const float* gamma = (const float*)d_in[6];
    const float* beta = (const float*)d_in[7];
    const float* l1W = (const float*)d_in[8];
    const float* l1b = (const float*)d_in[9];
    const float* l2W = (const float*)d_in[10];
    const float* l2b = (const float*)d_in[11];
    float* out = (float*)d_out;

    char* ws = (char*)d_ws;
    size_t off = 0;
    auto alloc = [&](size_t bytes) {
        void* p = ws + off;
        off += (bytes + 255) & ~(size_t)255;
        return p;
    };
    float* dinv = (float*)alloc((size_t)NREL * NN * sizeof(float));
    int* rstart = (int*)alloc((size_t)NREL * NN * sizeof(int));
    int* rend = (int*)alloc((size_t)NREL * NN * sizeof(int));
    unsigned short* csr = (unsigned short*)alloc((size_t)NBK * BCAP * 2);            // 4.8 MB
    unsigned* wpack = (unsigned*)alloc((size_t)NBK * BCAP * 4);                      // 9.6 MB
    unsigned short* xb = (unsigned short*)alloc((size_t)NN * D * 2);                 // 12.8 MB
    unsigned short* h1b = (unsigned short*)alloc((size_t)NN * D * 2);                // 12.8 MB
    unsigned short* R2b = (unsigned short*)alloc((size_t)NN * D * 2);                // 12.8 MB
    unsigned short* Wt1 = (unsigned short*)alloc(128 * 512 * 2);
    unsigned short* Wt2 = (unsigned short*)alloc(128 * 512 * 2);
    unsigned short* Wt3 = (unsigned short*)alloc(128 * 128 * 2);
    float* bs1 = (float*)alloc(128 * sizeof(float));
    float* bs2 = (float*)alloc(128 * sizeof(float));
    float* bnsum = (float*)alloc(256 * sizeof(float));
    int* frag = (int*)alloc((size_t)NREL * NRANGE * NCH * FCAP * 4);                 // 19.3 MB
    int* cntg = (int*)alloc((size_t)NREL * NRANGE * NCH * 4);                        // 0.2 MB

    k_pre<<<CAST_BLKS + 321, 256, 0, stream>>>(x, W1, W2, l1W, b1, b2, xb, Wt1, Wt2, Wt3,
                                               bs1, bs2, bnsum);
    dim3 bgrid(NCH, NREL);
    k_bin<<<bgrid, 256, 0, stream>>>(ei, frag, cntg);
    dim3 sgrid(NRANGE, NREL);
    k_sortb<<<sgrid, 512, 0, stream>>>(frag, cntg, csr, rstart, rend, dinv);
    k_wei<<<(NBK * BCAP) / 256, 256, 0, stream>>>(csr, dinv, wpack);

    // layer 1: fused aggregate(all 4 rels -> LDS) + K=512 GEMM -> h1b
    k_fused<false><<<NTILE, 256, 0, stream>>>(xb, wpack, rstart, rend, dinv, Wt1, bs1, h1b, nullptr);
    // layer 2: same + BN stats -> R2b, bnsum
    k_fused<true><<<NTILE, 256, 0, stream>>>(h1b, wpack, rstart, rend, dinv, Wt2, bs2, R2b, bnsum);
    // fused BN + MLP head
    k_final<<<(NN + 255) / 256, 256, 0, stream>>>(R2b, bnsum, gamma, beta, Wt3, l1b, l2W, l2b, out);
}